// Round 1
// baseline (1871.476 us; speedup 1.0000x reference)
//
#include <hip/hip_runtime.h>
#include <hip/hip_bf16.h>

#define HH 64          // hidden
#define FF 128         // in-feat
#define CC 10          // classes
#define LL 4           // layers

// BN eval-mode: y = x * (g / sqrt(1 + 1e-5)) + bt
#define BN_RSQRT 0.9999950000374997f

// h = relu(x @ W0 + b0), x:[N,128], W0:[128,64]
__global__ __launch_bounds__(256) void lin0_kernel(
    const float* __restrict__ x, const float* __restrict__ W0,
    const float* __restrict__ b0, float* __restrict__ h, int nrows)
{
    int wave = threadIdx.x >> 6;
    int lane = threadIdx.x & 63;
    int row = blockIdx.x * 4 + wave;
    if (row >= nrows) return;
    float v0 = x[(size_t)row * FF + lane];
    float v1 = x[(size_t)row * FF + 64 + lane];
    float acc = b0[lane];
#pragma unroll
    for (int k = 0; k < 64; ++k) {
        acc = fmaf(__shfl(v0, k, 64), W0[k * HH + lane], acc);
        acc = fmaf(__shfl(v1, k, 64), W0[(k + 64) * HH + lane], acc);
    }
    h[(size_t)row * HH + lane] = fmaxf(acc, 0.0f);
}

// agg[dst[e]][f] += h[src[e]][f]  (one wave per edge, lane = feature)
__global__ __launch_bounds__(256) void scatter_add_kernel(
    const int* __restrict__ src, const int* __restrict__ dst,
    const float* __restrict__ h, float* __restrict__ agg, int nedges)
{
    int idx = blockIdx.x * 256 + threadIdx.x;
    int e = idx >> 6;
    if (e >= nedges) return;
    int f = idx & 63;
    int s = src[e];   // wave-uniform -> scalar load
    int d = dst[e];
    atomicAdd(&agg[(size_t)d * HH + f], h[(size_t)s * HH + f]);
}

// out = relu( maybe_bn( (in [+ add]) @ W + b ) ), all [64,64]
// scale/shift nullable (bn); add nullable.
__global__ __launch_bounds__(256) void gemm64_kernel(
    const float* __restrict__ in, const float* __restrict__ add,
    const float* __restrict__ W, const float* __restrict__ bias,
    const float* __restrict__ g, const float* __restrict__ bt,
    float* __restrict__ out, int nrows)
{
    int wave = threadIdx.x >> 6;
    int lane = threadIdx.x & 63;
    int row = blockIdx.x * 4 + wave;
    if (row >= nrows) return;
    float v = in[(size_t)row * HH + lane];
    if (add) v += add[(size_t)row * HH + lane];
    float acc = bias[lane];
#pragma unroll
    for (int k = 0; k < 64; ++k) {
        acc = fmaf(__shfl(v, k, 64), W[k * HH + lane], acc);
    }
    if (g) acc = fmaf(acc, g[lane] * BN_RSQRT, bt[lane]);
    acc = fmaxf(acc, 0.0f);
    out[(size_t)row * HH + lane] = acc;
}

// one block (64 threads) per graph; batch sorted -> binary search bounds
__global__ __launch_bounds__(64) void pool_mean_kernel(
    const float* __restrict__ h, const int* __restrict__ batch,
    float* __restrict__ pooled, int nnodes)
{
    int gidx = blockIdx.x;
    int lane = threadIdx.x;
    int lo = 0, hi = nnodes;
    while (lo < hi) { int mid = (lo + hi) >> 1; if (batch[mid] < gidx) lo = mid + 1; else hi = mid; }
    int start = lo;
    lo = start; hi = nnodes;
    while (lo < hi) { int mid = (lo + hi) >> 1; if (batch[mid] < gidx + 1) lo = mid + 1; else hi = mid; }
    int end = lo;
    float acc = 0.0f;
    for (int i = start; i < end; ++i) acc += h[(size_t)i * HH + lane];
    float cnt = (float)(end - start);
    pooled[gidx * HH + lane] = acc / fmaxf(cnt, 1.0f);
}

// out = softmax(pooled @ Wl2 + bl2), pooled:[G,64], Wl2:[64,10]
__global__ __launch_bounds__(64) void head_kernel(
    const float* __restrict__ pooled, const float* __restrict__ Wl2,
    const float* __restrict__ bl2, float* __restrict__ out, int ngraphs)
{
    int gidx = blockIdx.x * 64 + threadIdx.x;
    if (gidx >= ngraphs) return;
    float logits[CC];
#pragma unroll
    for (int c = 0; c < CC; ++c) logits[c] = bl2[c];
    for (int k = 0; k < HH; ++k) {
        float p = pooled[gidx * HH + k];
#pragma unroll
        for (int c = 0; c < CC; ++c) logits[c] = fmaf(p, Wl2[k * CC + c], logits[c]);
    }
    float m = logits[0];
#pragma unroll
    for (int c = 1; c < CC; ++c) m = fmaxf(m, logits[c]);
    float ssum = 0.0f;
#pragma unroll
    for (int c = 0; c < CC; ++c) { logits[c] = __expf(logits[c] - m); ssum += logits[c]; }
    float inv = 1.0f / ssum;
#pragma unroll
    for (int c = 0; c < CC; ++c) out[gidx * CC + c] = logits[c] * inv;
}

extern "C" void kernel_launch(void* const* d_in, const int* in_sizes, int n_in,
                              void* d_out, int out_size, void* d_ws, size_t ws_size,
                              hipStream_t stream) {
    const float* x      = (const float*)d_in[0];
    const int*   ei     = (const int*)  d_in[1];
    const int*   batch  = (const int*)  d_in[3];
    const float* W0     = (const float*)d_in[4];
    const float* b0     = (const float*)d_in[5];
    const float* convW1 = (const float*)d_in[6];
    const float* convb1 = (const float*)d_in[7];
    const float* convg1 = (const float*)d_in[8];
    const float* convbt1= (const float*)d_in[9];
    const float* convW2 = (const float*)d_in[10];
    const float* convb2 = (const float*)d_in[11];
    const float* convg2 = (const float*)d_in[12];
    const float* convbt2= (const float*)d_in[13];
    const float* Wl1    = (const float*)d_in[14];
    const float* bl1    = (const float*)d_in[15];
    const float* Wl2    = (const float*)d_in[16];
    const float* bl2    = (const float*)d_in[17];

    const int N = in_sizes[0] / FF;       // 100000
    const int E = in_sizes[1] / 2;        // 1000000
    const int G = out_size / CC;          // 128

    float* h      = (float*)d_ws;
    float* tmp    = h + (size_t)N * HH;
    float* pooled = tmp + (size_t)N * HH;

    const int* src = ei;       // ei[0,:]
    const int* dst = ei + E;   // ei[1,:]

    int gemm_blocks = (N + 3) / 4;
    int scat_blocks = (int)(((size_t)E * HH + 255) / 256);

    lin0_kernel<<<gemm_blocks, 256, 0, stream>>>(x, W0, b0, h, N);

    for (int l = 0; l < LL; ++l) {
        hipMemsetAsync(tmp, 0, (size_t)N * HH * sizeof(float), stream);
        scatter_add_kernel<<<scat_blocks, 256, 0, stream>>>(src, dst, h, tmp, E);
        // z2 = relu(bn((h + agg) @ W1 + b1))  -> tmp (in-place per-row safe)
        gemm64_kernel<<<gemm_blocks, 256, 0, stream>>>(
            h, tmp, convW1 + (size_t)l * HH * HH, convb1 + l * HH,
            convg1 + l * HH, convbt1 + l * HH, tmp, N);
        // h = relu(bn(z2 @ W2 + b2))
        gemm64_kernel<<<gemm_blocks, 256, 0, stream>>>(
            tmp, nullptr, convW2 + (size_t)l * HH * HH, convb2 + l * HH,
            convg2 + l * HH, convbt2 + l * HH, h, N);
    }

    // hl = relu(h @ Wl1 + bl1) -> tmp
    gemm64_kernel<<<gemm_blocks, 256, 0, stream>>>(
        h, nullptr, Wl1, bl1, nullptr, nullptr, tmp, N);

    pool_mean_kernel<<<G, 64, 0, stream>>>(tmp, batch, pooled, N);
    head_kernel<<<(G + 63) / 64, 64, 0, stream>>>(pooled, Wl2, bl2, (float*)d_out, G);
}

// Round 2
// 984.660 us; speedup vs baseline: 1.9006x; 1.9006x over previous
//
#include <hip/hip_runtime.h>
#include <hip/hip_bf16.h>

#define HH 64          // hidden
#define FF 128         // in-feat
#define CC 10          // classes
#define LL 4           // layers
#define BN_RSQRT 0.9999950000374997f   // 1/sqrt(1+1e-5)

// ---------- storage type helpers (f32 compute, T storage) ----------
template <typename T> __device__ __forceinline__ float ldT(const T* p);
template <> __device__ __forceinline__ float ldT<float>(const float* p) { return *p; }
template <> __device__ __forceinline__ float ldT<__hip_bfloat16>(const __hip_bfloat16* p) { return __bfloat162float(*p); }
template <typename T> __device__ __forceinline__ void stT(T* p, float v);
template <> __device__ __forceinline__ void stT<float>(float* p, float v) { *p = v; }
template <> __device__ __forceinline__ void stT<__hip_bfloat16>(__hip_bfloat16* p, float v) { *p = __float2bfloat16(v); }

// wave-uniform broadcast of lane k (k is a literal after unroll -> v_readlane)
__device__ __forceinline__ float bcast(float v, int k) {
    return __uint_as_float(__builtin_amdgcn_readlane(__float_as_uint(v), k));
}

// ---------- lin0: h = relu(x @ W0 + b0), x:[N,128] f32, out T ----------
template <typename T>
__global__ __launch_bounds__(256) void lin0_kernel(
    const float* __restrict__ x, const float* __restrict__ W0,
    const float* __restrict__ b0, T* __restrict__ h, int nrows)
{
    int wave = threadIdx.x >> 6, lane = threadIdx.x & 63;
    int r0 = (blockIdx.x * 4 + wave) * 4;
    if (r0 >= nrows) return;
    float a[4], b[4];
#pragma unroll
    for (int r = 0; r < 4; ++r) {
        int row = r0 + r;
        a[r] = (row < nrows) ? x[(size_t)row * FF + lane] : 0.0f;
        b[r] = (row < nrows) ? x[(size_t)row * FF + 64 + lane] : 0.0f;
    }
    float acc[4];
    float bias = b0[lane];
#pragma unroll
    for (int r = 0; r < 4; ++r) acc[r] = bias;
#pragma unroll
    for (int k = 0; k < 64; ++k) {
        float w0 = W0[k * HH + lane];
        float w1 = W0[(k + 64) * HH + lane];
#pragma unroll
        for (int r = 0; r < 4; ++r) {
            acc[r] = fmaf(bcast(a[r], k), w0, acc[r]);
            acc[r] = fmaf(bcast(b[r], k), w1, acc[r]);
        }
    }
#pragma unroll
    for (int r = 0; r < 4; ++r) {
        int row = r0 + r;
        if (row < nrows) stT(&h[(size_t)row * HH + lane], fmaxf(acc[r], 0.0f));
    }
}

// ---------- CSR build ----------
__global__ __launch_bounds__(256) void hist_kernel(
    const int* __restrict__ dst, int* __restrict__ deg, int nedges)
{
    int e = blockIdx.x * 256 + threadIdx.x;
    if (e < nedges) atomicAdd(&deg[dst[e]], 1);
}

// per-block exclusive scan of deg -> rowptr, block sums -> partials
__global__ __launch_bounds__(256) void scan_block_kernel(
    const int* __restrict__ deg, int* __restrict__ rowptr,
    int* __restrict__ partials, int n)
{
    __shared__ int sm[256];
    int tid = threadIdx.x;
    int i = blockIdx.x * 256 + tid;
    int v = (i < n) ? deg[i] : 0;
    sm[tid] = v;
    __syncthreads();
    for (int ofs = 1; ofs < 256; ofs <<= 1) {
        int t = (tid >= ofs) ? sm[tid - ofs] : 0;
        __syncthreads();
        sm[tid] += t;
        __syncthreads();
    }
    if (i < n) rowptr[i] = sm[tid] - v;
    if (tid == 255) partials[blockIdx.x] = sm[255];
}

__global__ void scan_partials_kernel(int* partials, int nb)
{
    if (threadIdx.x == 0 && blockIdx.x == 0) {
        int run = 0;
        for (int i = 0; i < nb; ++i) { int t = partials[i]; partials[i] = run; run += t; }
    }
}

__global__ __launch_bounds__(256) void add_offsets_kernel(
    int* __restrict__ rowptr, const int* __restrict__ partials, int n)
{
    int i = blockIdx.x * 256 + threadIdx.x;
    if (i < n) rowptr[i] += partials[blockIdx.x];
}

// deg must be zeroed before this; restores deg as a side effect
__global__ __launch_bounds__(256) void place_kernel(
    const int* __restrict__ src, const int* __restrict__ dst,
    const int* __restrict__ rowptr, int* __restrict__ deg,
    int* __restrict__ csr, int nedges)
{
    int e = blockIdx.x * 256 + threadIdx.x;
    if (e >= nedges) return;
    int d = dst[e];
    int slot = atomicAdd(&deg[d], 1);
    csr[rowptr[d] + slot] = src[e];
}

// ---------- fused layer: z = h + gather; z2 = relu(bn(z@W1+b1)); out = relu(bn(z2@W2+b2)) ----------
template <typename T>
__global__ __launch_bounds__(256) void layer_kernel(
    const T* __restrict__ h, const int* __restrict__ rowptr,
    const int* __restrict__ deg, const int* __restrict__ csr,
    const float* __restrict__ W1, const float* __restrict__ b1,
    const float* __restrict__ g1, const float* __restrict__ bt1,
    const float* __restrict__ W2, const float* __restrict__ b2,
    const float* __restrict__ g2, const float* __restrict__ bt2,
    T* __restrict__ out, int nrows)
{
    int wave = threadIdx.x >> 6, lane = threadIdx.x & 63;
    int r0 = (blockIdx.x * 4 + wave) * 4;
    if (r0 >= nrows) return;

    float z[4] = {0.f, 0.f, 0.f, 0.f};
#pragma unroll
    for (int r = 0; r < 4; ++r) {
        int row = r0 + r;
        if (row < nrows) {
            z[r] = ldT(&h[(size_t)row * HH + lane]);
            int s = rowptr[row], c = deg[row];
            for (int j = 0; j < c; ++j) {
                int sn = csr[s + j];
                z[r] += ldT(&h[(size_t)sn * HH + lane]);
            }
        }
    }

    // GEMM1 + BN + ReLU
    float t[4];
    {
        float bias = b1[lane];
#pragma unroll
        for (int r = 0; r < 4; ++r) t[r] = bias;
#pragma unroll
        for (int k = 0; k < 64; ++k) {
            float w = W1[k * HH + lane];
#pragma unroll
            for (int r = 0; r < 4; ++r) t[r] = fmaf(bcast(z[r], k), w, t[r]);
        }
        float gs = g1[lane] * BN_RSQRT, bo = bt1[lane];
#pragma unroll
        for (int r = 0; r < 4; ++r) t[r] = fmaxf(fmaf(t[r], gs, bo), 0.0f);
    }

    // GEMM2 + BN + ReLU
    {
        float bias = b2[lane];
#pragma unroll
        for (int r = 0; r < 4; ++r) z[r] = bias;
#pragma unroll
        for (int k = 0; k < 64; ++k) {
            float w = W2[k * HH + lane];
#pragma unroll
            for (int r = 0; r < 4; ++r) z[r] = fmaf(bcast(t[r], k), w, z[r]);
        }
        float gs = g2[lane] * BN_RSQRT, bo = bt2[lane];
#pragma unroll
        for (int r = 0; r < 4; ++r) z[r] = fmaxf(fmaf(z[r], gs, bo), 0.0f);
    }

#pragma unroll
    for (int r = 0; r < 4; ++r) {
        int row = r0 + r;
        if (row < nrows) stT(&out[(size_t)row * HH + lane], z[r]);
    }
}

// ---------- fused final linear + mean-pool partials ----------
// each wave owns 64 consecutive rows; flush per-graph partial on batch change
template <typename T>
__global__ __launch_bounds__(256) void poolgemm_kernel(
    const T* __restrict__ h, const int* __restrict__ batch,
    const float* __restrict__ Wl1, const float* __restrict__ bl1,
    float* __restrict__ pooled, float* __restrict__ cnt, int nrows)
{
    int wave = threadIdx.x >> 6, lane = threadIdx.x & 63;
    int base = (blockIdx.x * 4 + wave) * 64;
    if (base >= nrows) return;
    int lim = min(base + 64, nrows);

    float acc = 0.0f;
    int curg = -1, runcnt = 0;
    float bias = bl1[lane];

    for (int rb = base; rb < lim; rb += 4) {
        float z[4], t[4];
#pragma unroll
        for (int r = 0; r < 4; ++r) {
            int row = rb + r;
            z[r] = (row < lim) ? ldT(&h[(size_t)row * HH + lane]) : 0.0f;
            t[r] = bias;
        }
#pragma unroll
        for (int k = 0; k < 64; ++k) {
            float w = Wl1[k * HH + lane];
#pragma unroll
            for (int r = 0; r < 4; ++r) t[r] = fmaf(bcast(z[r], k), w, t[r]);
        }
#pragma unroll
        for (int r = 0; r < 4; ++r) {
            int row = rb + r;
            if (row < lim) {
                float hv = fmaxf(t[r], 0.0f);
                int g = batch[row];
                if (g != curg) {
                    if (curg >= 0) {
                        atomicAdd(&pooled[curg * HH + lane], acc);
                        if (lane == 0) atomicAdd(&cnt[curg], (float)runcnt);
                    }
                    curg = g; acc = hv; runcnt = 1;
                } else { acc += hv; runcnt += 1; }
            }
        }
    }
    if (curg >= 0) {
        atomicAdd(&pooled[curg * HH + lane], acc);
        if (lane == 0) atomicAdd(&cnt[curg], (float)runcnt);
    }
}

// ---------- head: softmax((pooled/cnt) @ Wl2 + bl2) ----------
__global__ __launch_bounds__(64) void head_kernel(
    const float* __restrict__ pooled, const float* __restrict__ cnt,
    const float* __restrict__ Wl2, const float* __restrict__ bl2,
    float* __restrict__ out, int ngraphs)
{
    int gidx = blockIdx.x * 64 + threadIdx.x;
    if (gidx >= ngraphs) return;
    float logits[CC];
#pragma unroll
    for (int c = 0; c < CC; ++c) logits[c] = bl2[c];
    float inv_n = 1.0f / fmaxf(cnt[gidx], 1.0f);
    for (int k = 0; k < HH; ++k) {
        float p = pooled[gidx * HH + k] * inv_n;
#pragma unroll
        for (int c = 0; c < CC; ++c) logits[c] = fmaf(p, Wl2[k * CC + c], logits[c]);
    }
    float m = logits[0];
#pragma unroll
    for (int c = 1; c < CC; ++c) m = fmaxf(m, logits[c]);
    float ssum = 0.0f;
#pragma unroll
    for (int c = 0; c < CC; ++c) { logits[c] = __expf(logits[c] - m); ssum += logits[c]; }
    float inv = 1.0f / ssum;
#pragma unroll
    for (int c = 0; c < CC; ++c) out[gidx * CC + c] = logits[c] * inv;
}

// ---------- driver ----------
template <typename T>
static void run_net(const float* x, const int* src, const int* dst, const int* batch,
                    const float* W0, const float* b0,
                    const float* convW1, const float* convb1, const float* convg1, const float* convbt1,
                    const float* convW2, const float* convb2, const float* convg2, const float* convbt2,
                    const float* Wl1, const float* bl1, const float* Wl2, const float* bl2,
                    float* out, int N, int E, int G,
                    int* rowptr, int* deg, int* csr, float* pooled, float* cnt,
                    T* hA, T* hB, hipStream_t stream)
{
    int NB = (N + 255) / 256;
    int EB = (E + 255) / 256;
    int gemm_blocks = (N + 15) / 16;       // 16 rows/block
    int pool_blocks = ((N + 63) / 64 + 3) / 4;

    // CSR build
    hipMemsetAsync(deg, 0, (size_t)N * sizeof(int), stream);
    hist_kernel<<<EB, 256, 0, stream>>>(dst, deg, E);
    scan_block_kernel<<<NB, 256, 0, stream>>>(deg, rowptr, csr /*reuse as partials*/, N);
    scan_partials_kernel<<<1, 64, 0, stream>>>(csr, NB);
    add_offsets_kernel<<<NB, 256, 0, stream>>>(rowptr, csr, N);
    hipMemsetAsync(deg, 0, (size_t)N * sizeof(int), stream);
    place_kernel<<<EB, 256, 0, stream>>>(src, dst, rowptr, deg, csr, E);

    // lin0
    lin0_kernel<T><<<gemm_blocks, 256, 0, stream>>>(x, W0, b0, hA, N);

    // layers
    const T* hin = hA; T* hout = hB;
    for (int l = 0; l < LL; ++l) {
        layer_kernel<T><<<gemm_blocks, 256, 0, stream>>>(
            hin, rowptr, deg, csr,
            convW1 + (size_t)l * HH * HH, convb1 + l * HH, convg1 + l * HH, convbt1 + l * HH,
            convW2 + (size_t)l * HH * HH, convb2 + l * HH, convg2 + l * HH, convbt2 + l * HH,
            (T*)hout, N);
        const T* tswap = hin; hin = hout; hout = (T*)tswap;
    }

    // final linear + pool
    hipMemsetAsync(pooled, 0, (size_t)G * HH * sizeof(float), stream);
    hipMemsetAsync(cnt, 0, (size_t)G * sizeof(float), stream);
    poolgemm_kernel<T><<<pool_blocks, 256, 0, stream>>>(hin, batch, Wl1, bl1, pooled, cnt, N);
    head_kernel<<<(G + 63) / 64, 64, 0, stream>>>(pooled, cnt, Wl2, bl2, out, G);
}

extern "C" void kernel_launch(void* const* d_in, const int* in_sizes, int n_in,
                              void* d_out, int out_size, void* d_ws, size_t ws_size,
                              hipStream_t stream) {
    const float* x      = (const float*)d_in[0];
    const int*   ei     = (const int*)  d_in[1];
    const int*   batch  = (const int*)  d_in[3];
    const float* W0     = (const float*)d_in[4];
    const float* b0     = (const float*)d_in[5];
    const float* convW1 = (const float*)d_in[6];
    const float* convb1 = (const float*)d_in[7];
    const float* convg1 = (const float*)d_in[8];
    const float* convbt1= (const float*)d_in[9];
    const float* convW2 = (const float*)d_in[10];
    const float* convb2 = (const float*)d_in[11];
    const float* convg2 = (const float*)d_in[12];
    const float* convbt2= (const float*)d_in[13];
    const float* Wl1    = (const float*)d_in[14];
    const float* bl1    = (const float*)d_in[15];
    const float* Wl2    = (const float*)d_in[16];
    const float* bl2    = (const float*)d_in[17];

    const int N = in_sizes[0] / FF;
    const int E = in_sizes[1] / 2;
    const int G = out_size / CC;

    const int* src = ei;
    const int* dst = ei + E;

    // workspace layout (256B aligned slots)
    size_t off = 0;
    auto take = [&](size_t bytes) { size_t p = off; off = (off + bytes + 255) & ~255ULL; return p; };
    size_t o_rowptr = take((size_t)N * 4);
    size_t o_deg    = take((size_t)N * 4);
    size_t o_csr    = take((size_t)(E > ((N + 255) / 256) ? E : ((N + 255) / 256)) * 4); // also reused as scan partials
    size_t o_pooled = take((size_t)G * HH * 4);
    size_t o_cnt    = take((size_t)G * 4);
    size_t o_fixed_end = off;

    char* base = (char*)d_ws;
    int*   rowptr = (int*)(base + o_rowptr);
    int*   deg    = (int*)(base + o_deg);
    int*   csr    = (int*)(base + o_csr);
    float* pooled = (float*)(base + o_pooled);
    float* cnt    = (float*)(base + o_cnt);

    size_t need_f32 = o_fixed_end + 2 * (((size_t)N * HH * 4 + 255) & ~255ULL);

    if (ws_size >= need_f32) {
        size_t o_hA = take((size_t)N * HH * 4);
        size_t o_hB = take((size_t)N * HH * 4);
        run_net<float>(x, src, dst, batch, W0, b0,
                       convW1, convb1, convg1, convbt1, convW2, convb2, convg2, convbt2,
                       Wl1, bl1, Wl2, bl2, (float*)d_out, N, E, G,
                       rowptr, deg, csr, pooled, cnt,
                       (float*)(base + o_hA), (float*)(base + o_hB), stream);
    } else {
        size_t o_hA = take((size_t)N * HH * 2);
        size_t o_hB = take((size_t)N * HH * 2);
        run_net<__hip_bfloat16>(x, src, dst, batch, W0, b0,
                       convW1, convb1, convg1, convbt1, convW2, convb2, convg2, convbt2,
                       Wl1, bl1, Wl2, bl2, (float*)d_out, N, E, G,
                       rowptr, deg, csr, pooled, cnt,
                       (__hip_bfloat16*)(base + o_hA), (__hip_bfloat16*)(base + o_hB), stream);
    }
}

// Round 3
// 675.571 us; speedup vs baseline: 2.7702x; 1.4575x over previous
//
#include <hip/hip_runtime.h>
#include <hip/hip_bf16.h>

#define HH 64          // hidden
#define FF 128         // in-feat
#define CC 10          // classes
#define LL 4           // layers
#define ROWS 8         // rows per wave in fused kernels
#define BN_RSQRT 0.9999950000374997f   // 1/sqrt(1+1e-5)

typedef __hip_bfloat16 bf16;

__device__ __forceinline__ float ldbf(const bf16* p) {
    return __uint_as_float(((unsigned)*(const unsigned short*)p) << 16);
}
__device__ __forceinline__ void stbf(bf16* p, float v) {
    *p = __float2bfloat16(v);
}
// wave-uniform broadcast of lane k (k may be dynamic uniform -> v_readlane)
__device__ __forceinline__ float bcast(float v, int k) {
    return __uint_as_float(__builtin_amdgcn_readlane(__float_as_uint(v), k));
}

// ---------- lin0: h = relu(x @ W0 + b0), x:[N,128] f32, out bf16 ----------
__global__ __launch_bounds__(256) void lin0_kernel(
    const float* __restrict__ x, const float* __restrict__ W0,
    const float* __restrict__ b0, bf16* __restrict__ h, int nrows)
{
    int wave = __builtin_amdgcn_readfirstlane(threadIdx.x >> 6);
    int lane = threadIdx.x & 63;
    int r0 = (blockIdx.x * 4 + wave) * ROWS;
    if (r0 >= nrows) return;

    float a[ROWS], b[ROWS], acc[ROWS];
    float bias = b0[lane];
#pragma unroll
    for (int r = 0; r < ROWS; ++r) {
        int row = r0 + r;
        a[r] = (row < nrows) ? x[(size_t)row * FF + lane] : 0.0f;
        b[r] = (row < nrows) ? x[(size_t)row * FF + 64 + lane] : 0.0f;
        acc[r] = bias;
    }
#pragma unroll 8
    for (int k = 0; k < 64; ++k) {
        float w0 = W0[k * HH + lane];
        float w1 = W0[(k + 64) * HH + lane];
#pragma unroll
        for (int r = 0; r < ROWS; ++r) {
            acc[r] = fmaf(bcast(a[r], k), w0, acc[r]);
            acc[r] = fmaf(bcast(b[r], k), w1, acc[r]);
        }
    }
#pragma unroll
    for (int r = 0; r < ROWS; ++r) {
        int row = r0 + r;
        if (row < nrows) stbf(&h[(size_t)row * HH + lane], fmaxf(acc[r], 0.0f));
    }
}

// ---------- CSR build ----------
__global__ __launch_bounds__(256) void hist_kernel(
    const int* __restrict__ dst, int* __restrict__ deg, int nedges)
{
    int e = blockIdx.x * 256 + threadIdx.x;
    if (e < nedges) atomicAdd(&deg[dst[e]], 1);
}

__global__ __launch_bounds__(256) void scan_block_kernel(
    const int* __restrict__ deg, int* __restrict__ rowptr,
    int* __restrict__ partials, int n)
{
    __shared__ int sm[256];
    int tid = threadIdx.x;
    int i = blockIdx.x * 256 + tid;
    int v = (i < n) ? deg[i] : 0;
    sm[tid] = v;
    __syncthreads();
    for (int ofs = 1; ofs < 256; ofs <<= 1) {
        int t = (tid >= ofs) ? sm[tid - ofs] : 0;
        __syncthreads();
        sm[tid] += t;
        __syncthreads();
    }
    if (i < n) rowptr[i] = sm[tid] - v;
    if (tid == 255) partials[blockIdx.x] = sm[255];
}

__global__ void scan_partials_kernel(int* partials, int nb)
{
    if (threadIdx.x == 0 && blockIdx.x == 0) {
        int run = 0;
        for (int i = 0; i < nb; ++i) { int t = partials[i]; partials[i] = run; run += t; }
    }
}

__global__ __launch_bounds__(256) void add_offsets_kernel(
    int* __restrict__ rowptr, const int* __restrict__ partials, int n)
{
    int i = blockIdx.x * 256 + threadIdx.x;
    if (i < n) rowptr[i] += partials[blockIdx.x];
}

__global__ __launch_bounds__(256) void place_kernel(
    const int* __restrict__ src, const int* __restrict__ dst,
    const int* __restrict__ rowptr, int* __restrict__ deg,
    int* __restrict__ csr, int nedges)
{
    int e = blockIdx.x * 256 + threadIdx.x;
    if (e >= nedges) return;
    int d = dst[e];
    int slot = atomicAdd(&deg[d], 1);
    csr[rowptr[d] + slot] = src[e];
}

// ---------- fused layer ----------
__global__ __launch_bounds__(256) void layer_kernel(
    const bf16* __restrict__ h, const int* __restrict__ rowptr,
    const int* __restrict__ deg, const int* __restrict__ csr,
    const float* __restrict__ W1, const float* __restrict__ b1,
    const float* __restrict__ g1, const float* __restrict__ bt1,
    const float* __restrict__ W2, const float* __restrict__ b2,
    const float* __restrict__ g2, const float* __restrict__ bt2,
    bf16* __restrict__ out, int nrows)
{
    int wave = __builtin_amdgcn_readfirstlane(threadIdx.x >> 6);
    int lane = threadIdx.x & 63;
    int r0 = (blockIdx.x * 4 + wave) * ROWS;
    if (r0 >= nrows) return;

    // wave-uniform row metadata -> scalar loads
    int s[ROWS], c[ROWS], maxc = 0;
#pragma unroll
    for (int r = 0; r < ROWS; ++r) {
        int row = r0 + r;
        if (row < nrows) { s[r] = rowptr[row]; c[r] = deg[row]; }
        else { s[r] = 0; c[r] = 0; }
        maxc = max(maxc, c[r]);
    }

    float z[ROWS];
#pragma unroll
    for (int r = 0; r < ROWS; ++r)
        z[r] = (r0 + r < nrows) ? ldbf(&h[(size_t)(r0 + r) * HH + lane]) : 0.0f;

    // interleaved gather: 8 independent load chains, straight-line body
    for (int j = 0; j < maxc; ++j) {
        float v[ROWS];
#pragma unroll
        for (int r = 0; r < ROWS; ++r) {
            int jj = min(j, max(c[r] - 1, 0));
            int sn = csr[s[r] + jj];                 // uniform -> s_load
            sn = min(max(sn, 0), nrows - 1);         // SALU clamp, fault-proof
            v[r] = ldbf(&h[(size_t)sn * HH + lane]);
        }
#pragma unroll
        for (int r = 0; r < ROWS; ++r)
            z[r] += (j < c[r]) ? v[r] : 0.0f;
    }

    // GEMM1 + BN + ReLU
    float t[ROWS];
    {
        float bias = b1[lane];
#pragma unroll
        for (int r = 0; r < ROWS; ++r) t[r] = bias;
#pragma unroll 8
        for (int k = 0; k < 64; ++k) {
            float w = W1[k * HH + lane];
#pragma unroll
            for (int r = 0; r < ROWS; ++r) t[r] = fmaf(bcast(z[r], k), w, t[r]);
        }
        float gs = g1[lane] * BN_RSQRT, bo = bt1[lane];
#pragma unroll
        for (int r = 0; r < ROWS; ++r) t[r] = fmaxf(fmaf(t[r], gs, bo), 0.0f);
    }
    // GEMM2 + BN + ReLU
    {
        float bias = b2[lane];
#pragma unroll
        for (int r = 0; r < ROWS; ++r) z[r] = bias;
#pragma unroll 8
        for (int k = 0; k < 64; ++k) {
            float w = W2[k * HH + lane];
#pragma unroll
            for (int r = 0; r < ROWS; ++r) z[r] = fmaf(bcast(t[r], k), w, z[r]);
        }
        float gs = g2[lane] * BN_RSQRT, bo = bt2[lane];
#pragma unroll
        for (int r = 0; r < ROWS; ++r) z[r] = fmaxf(fmaf(z[r], gs, bo), 0.0f);
    }

#pragma unroll
    for (int r = 0; r < ROWS; ++r) {
        int row = r0 + r;
        if (row < nrows) stbf(&out[(size_t)row * HH + lane], z[r]);
    }
}

// ---------- fused final linear + mean-pool partials ----------
__global__ __launch_bounds__(256) void poolgemm_kernel(
    const bf16* __restrict__ h, const int* __restrict__ batch,
    const float* __restrict__ Wl1, const float* __restrict__ bl1,
    float* __restrict__ pooled, float* __restrict__ cnt, int nrows)
{
    int wave = __builtin_amdgcn_readfirstlane(threadIdx.x >> 6);
    int lane = threadIdx.x & 63;
    int base = (blockIdx.x * 4 + wave) * 64;
    if (base >= nrows) return;
    int lim = min(base + 64, nrows);

    float acc = 0.0f;
    int curg = -1, runcnt = 0;
    float bias = bl1[lane];

    for (int rb = base; rb < lim; rb += 4) {
        float z[4], t[4];
#pragma unroll
        for (int r = 0; r < 4; ++r) {
            int row = rb + r;
            z[r] = (row < lim) ? ldbf(&h[(size_t)row * HH + lane]) : 0.0f;
            t[r] = bias;
        }
#pragma unroll 8
        for (int k = 0; k < 64; ++k) {
            float w = Wl1[k * HH + lane];
#pragma unroll
            for (int r = 0; r < 4; ++r) t[r] = fmaf(bcast(z[r], k), w, t[r]);
        }
#pragma unroll
        for (int r = 0; r < 4; ++r) {
            int row = rb + r;
            if (row < lim) {
                float hv = fmaxf(t[r], 0.0f);
                int g = batch[row];
                if (g != curg) {
                    if (curg >= 0) {
                        atomicAdd(&pooled[curg * HH + lane], acc);
                        if (lane == 0) atomicAdd(&cnt[curg], (float)runcnt);
                    }
                    curg = g; acc = hv; runcnt = 1;
                } else { acc += hv; runcnt += 1; }
            }
        }
    }
    if (curg >= 0) {
        atomicAdd(&pooled[curg * HH + lane], acc);
        if (lane == 0) atomicAdd(&cnt[curg], (float)runcnt);
    }
}

// ---------- head: softmax((pooled/cnt) @ Wl2 + bl2) ----------
__global__ __launch_bounds__(64) void head_kernel(
    const float* __restrict__ pooled, const float* __restrict__ cnt,
    const float* __restrict__ Wl2, const float* __restrict__ bl2,
    float* __restrict__ out, int ngraphs)
{
    int gidx = blockIdx.x * 64 + threadIdx.x;
    if (gidx >= ngraphs) return;
    float logits[CC];
#pragma unroll
    for (int c = 0; c < CC; ++c) logits[c] = bl2[c];
    float inv_n = 1.0f / fmaxf(cnt[gidx], 1.0f);
    for (int k = 0; k < HH; ++k) {
        float p = pooled[gidx * HH + k] * inv_n;
#pragma unroll
        for (int c = 0; c < CC; ++c) logits[c] = fmaf(p, Wl2[k * CC + c], logits[c]);
    }
    float m = logits[0];
#pragma unroll
    for (int c = 1; c < CC; ++c) m = fmaxf(m, logits[c]);
    float ssum = 0.0f;
#pragma unroll
    for (int c = 0; c < CC; ++c) { logits[c] = __expf(logits[c] - m); ssum += logits[c]; }
    float inv = 1.0f / ssum;
#pragma unroll
    for (int c = 0; c < CC; ++c) out[gidx * CC + c] = logits[c] * inv;
}

extern "C" void kernel_launch(void* const* d_in, const int* in_sizes, int n_in,
                              void* d_out, int out_size, void* d_ws, size_t ws_size,
                              hipStream_t stream) {
    const float* x      = (const float*)d_in[0];
    const int*   ei     = (const int*)  d_in[1];
    const int*   batch  = (const int*)  d_in[3];
    const float* W0     = (const float*)d_in[4];
    const float* b0     = (const float*)d_in[5];
    const float* convW1 = (const float*)d_in[6];
    const float* convb1 = (const float*)d_in[7];
    const float* convg1 = (const float*)d_in[8];
    const float* convbt1= (const float*)d_in[9];
    const float* convW2 = (const float*)d_in[10];
    const float* convb2 = (const float*)d_in[11];
    const float* convg2 = (const float*)d_in[12];
    const float* convbt2= (const float*)d_in[13];
    const float* Wl1    = (const float*)d_in[14];
    const float* bl1    = (const float*)d_in[15];
    const float* Wl2    = (const float*)d_in[16];
    const float* bl2    = (const float*)d_in[17];

    const int N = in_sizes[0] / FF;
    const int E = in_sizes[1] / 2;
    const int G = out_size / CC;

    const int* src = ei;
    const int* dst = ei + E;

    // workspace layout
    size_t off = 0;
    auto take = [&](size_t bytes) { size_t p = off; off = (off + bytes + 255) & ~255ULL; return p; };
    int NB = (N + 255) / 256;
    int EB = (E + 255) / 256;
    size_t o_rowptr = take((size_t)N * 4);
    size_t o_deg    = take((size_t)N * 4);
    size_t o_csr    = take((size_t)(E > NB ? E : NB) * 4 + 256); // +slack for clamped OOB reads
    size_t o_pooled = take((size_t)G * HH * 4);
    size_t o_cnt    = take((size_t)G * 4);
    size_t o_hA     = take((size_t)N * HH * 2);
    size_t o_hB     = take((size_t)N * HH * 2);

    char* base = (char*)d_ws;
    int*   rowptr = (int*)(base + o_rowptr);
    int*   deg    = (int*)(base + o_deg);
    int*   csr    = (int*)(base + o_csr);
    float* pooled = (float*)(base + o_pooled);
    float* cnt    = (float*)(base + o_cnt);
    bf16*  hA     = (bf16*)(base + o_hA);
    bf16*  hB     = (bf16*)(base + o_hB);

    int gemm_blocks = (N + 4 * ROWS - 1) / (4 * ROWS);
    int pool_blocks = ((N + 63) / 64 + 3) / 4;

    // CSR build
    hipMemsetAsync(deg, 0, (size_t)N * sizeof(int), stream);
    hist_kernel<<<EB, 256, 0, stream>>>(dst, deg, E);
    scan_block_kernel<<<NB, 256, 0, stream>>>(deg, rowptr, csr /*partials*/, N);
    scan_partials_kernel<<<1, 64, 0, stream>>>(csr, NB);
    add_offsets_kernel<<<NB, 256, 0, stream>>>(rowptr, csr, N);
    hipMemsetAsync(deg, 0, (size_t)N * sizeof(int), stream);
    place_kernel<<<EB, 256, 0, stream>>>(src, dst, rowptr, deg, csr, E);

    // lin0
    lin0_kernel<<<gemm_blocks, 256, 0, stream>>>(x, W0, b0, hA, N);

    // layers (ping-pong)
    const bf16* hin = hA; bf16* hout = hB;
    for (int l = 0; l < LL; ++l) {
        layer_kernel<<<gemm_blocks, 256, 0, stream>>>(
            hin, rowptr, deg, csr,
            convW1 + (size_t)l * HH * HH, convb1 + l * HH, convg1 + l * HH, convbt1 + l * HH,
            convW2 + (size_t)l * HH * HH, convb2 + l * HH, convg2 + l * HH, convbt2 + l * HH,
            hout, N);
        bf16* tswap = (bf16*)hin; hin = hout; hout = tswap;
    }

    // final linear + pool + head
    hipMemsetAsync(pooled, 0, (size_t)G * HH * sizeof(float), stream);
    hipMemsetAsync(cnt, 0, (size_t)G * sizeof(float), stream);
    poolgemm_kernel<<<pool_blocks, 256, 0, stream>>>(hin, batch, Wl1, bl1, pooled, cnt, N);
    head_kernel<<<(G + 63) / 64, 64, 0, stream>>>(pooled, cnt, Wl2, bl2, (float*)d_out, G);
}

// Round 4
// 491.627 us; speedup vs baseline: 3.8067x; 1.3742x over previous
//
#include <hip/hip_runtime.h>
#include <hip/hip_bf16.h>

#define HH 64
#define FF 128
#define CC 10
#define LL 4
#define BN_RSQRT 0.9999950000374997f   // 1/sqrt(1+1e-5)

typedef __hip_bfloat16 bf16;
using short8 = __attribute__((ext_vector_type(8))) short;
using f32x4  = __attribute__((ext_vector_type(4))) float;

__device__ __forceinline__ float ldbf(const bf16* p) {
    return __uint_as_float(((unsigned)*(const unsigned short*)p) << 16);
}
// RNE f32->bf16 bits (finite inputs)
__device__ __forceinline__ unsigned short f2bf(float v) {
    unsigned u = __float_as_uint(v);
    return (unsigned short)((u + 0x7FFFu + ((u >> 16) & 1u)) >> 16);
}
__device__ __forceinline__ float bcast(float v, int k) {
    return __uint_as_float(__builtin_amdgcn_readlane(__float_as_uint(v), k));
}

// ---------- weight fragment packing ----------
// B-frag layout for mfma_f32_16x16x32_bf16: lane l holds B[k][n] with
// n = tile*16 + (l&15), k = kc*32 + (l>>4)*8 + e, e=0..7.
// wf8[0..1023]            : W0   (128x64, KC=4, 16 frags)
// wf8[1024 + m*512 + ...] : conv m = layer*2+g (64x64, KC=2, 8 frags)
__global__ __launch_bounds__(256) void pack_weights_kernel(
    const float* __restrict__ W0, const float* __restrict__ convW1,
    const float* __restrict__ convW2, short* __restrict__ wf)
{
    int t = blockIdx.x * 256 + threadIdx.x;
    if (t >= 5120) return;
    const float* W;
    int fi, l, KC_tile, out_idx;
    if (t < 1024) {
        int local = t; fi = local >> 6; l = local & 63;
        int tile = fi >> 2, kc = fi & 3;
        W = W0;
        KC_tile = kc; out_idx = local;
        int k0 = KC_tile * 32 + (l >> 4) * 8;
        int n = tile * 16 + (l & 15);
#pragma unroll
        for (int e = 0; e < 8; ++e)
            wf[out_idx * 8 + e] = (short)f2bf(W[(k0 + e) * HH + n]);
    } else {
        int t2 = t - 1024;
        int m = t2 >> 9;          // 0..7 : layer*2+g
        int local = t2 & 511;
        fi = local >> 6; l = local & 63;
        int tile = fi >> 1, kc = fi & 1;
        int layer = m >> 1, g = m & 1;
        W = (g ? convW2 : convW1) + (size_t)layer * HH * HH;
        out_idx = 1024 + m * 512 + local;
        int k0 = kc * 32 + (l >> 4) * 8;
        int n = tile * 16 + (l & 15);
#pragma unroll
        for (int e = 0; e < 8; ++e)
            wf[out_idx * 8 + e] = (short)f2bf(W[(k0 + e) * HH + n]);
    }
}

// ---------- lin0 (MFMA): h = relu(x @ W0 + b0) ----------
__global__ __launch_bounds__(256) void lin0_kernel(
    const float* __restrict__ x, const short8* __restrict__ wf0,
    const float* __restrict__ b0, bf16* __restrict__ h, int nrows)
{
    __shared__ __align__(16) short lds_all[4][2048];   // per wave [16][128] bf16
    int wave = __builtin_amdgcn_readfirstlane(threadIdx.x >> 6);
    int lane = threadIdx.x & 63;
    char* ldsb = (char*)&lds_all[wave][0];
    int r0 = (blockIdx.x * 4 + wave) * 16;

    // stage x -> LDS bf16 (lane covers feature pair 2*lane, 2*lane+1)
#pragma unroll
    for (int r = 0; r < 16; ++r) {
        int row = r0 + r;
        float2 xv = make_float2(0.f, 0.f);
        if (row < nrows) xv = *(const float2*)(x + (size_t)row * FF + lane * 2);
        unsigned pk = (unsigned)f2bf(xv.x) | ((unsigned)f2bf(xv.y) << 16);
        *(int*)(ldsb + r * 256 + ((lane * 4) ^ ((r & 7) << 4))) = pk;
    }
    __syncthreads();

    short8 a[4];
#pragma unroll
    for (int kc = 0; kc < 4; ++kc) {
        int rr = lane & 15;
        a[kc] = *(const short8*)(ldsb + rr * 256 + (((kc * 64 + (lane >> 4) * 16)) ^ ((rr & 7) << 4)));
    }
    f32x4 acc[4];
#pragma unroll
    for (int tile = 0; tile < 4; ++tile) {
        acc[tile] = (f32x4){0.f, 0.f, 0.f, 0.f};
#pragma unroll
        for (int kc = 0; kc < 4; ++kc) {
            short8 b = wf0[(tile * 4 + kc) * 64 + lane];
            acc[tile] = __builtin_amdgcn_mfma_f32_16x16x32_bf16(a[kc], b, acc[tile], 0, 0, 0);
        }
    }
    __syncthreads();
    // epilogue: bias + relu -> LDS bf16 [16][64] (row stride 256B)
#pragma unroll
    for (int tile = 0; tile < 4; ++tile) {
        int col = tile * 16 + (lane & 15);
        float bia = b0[col];
#pragma unroll
        for (int q = 0; q < 4; ++q) {
            int row = (lane >> 4) * 4 + q;
            float v = fmaxf(acc[tile][q] + bia, 0.0f);
            *(short*)(ldsb + row * 256 + ((col * 2) ^ ((row & 7) << 4))) = (short)f2bf(v);
        }
    }
    __syncthreads();
#pragma unroll
    for (int half = 0; half < 2; ++half) {
        int row = (lane >> 3) + half * 8;
        short8 vv = *(const short8*)(ldsb + row * 256 + ((((lane & 7) * 16)) ^ ((row & 7) << 4)));
        int grow = r0 + row;
        if (grow < nrows)
            *(short8*)((char*)h + (size_t)grow * 128 + (lane & 7) * 16) = vv;
    }
}

// ---------- CSR build ----------
__global__ __launch_bounds__(256) void hist_kernel(
    const int* __restrict__ dst, int* __restrict__ deg, int nedges)
{
    int e = blockIdx.x * 256 + threadIdx.x;
    if (e < nedges) atomicAdd(&deg[dst[e]], 1);
}

__global__ __launch_bounds__(256) void scan_block_kernel(
    const int* __restrict__ deg, int* __restrict__ rowptr,
    int* __restrict__ partials, int n)
{
    __shared__ int sm[256];
    int tid = threadIdx.x;
    int i = blockIdx.x * 256 + tid;
    int v = (i < n) ? deg[i] : 0;
    sm[tid] = v;
    __syncthreads();
    for (int ofs = 1; ofs < 256; ofs <<= 1) {
        int t = (tid >= ofs) ? sm[tid - ofs] : 0;
        __syncthreads();
        sm[tid] += t;
        __syncthreads();
    }
    if (i < n) rowptr[i] = sm[tid] - v;
    if (tid == 255) partials[blockIdx.x] = sm[255];
}

// single block, chunked parallel exclusive scan of partials
__global__ __launch_bounds__(256) void scan_partials_kernel(int* partials, int nb)
{
    __shared__ int sm[256];
    __shared__ int carry;
    int tid = threadIdx.x;
    if (tid == 0) carry = 0;
    __syncthreads();
    for (int base = 0; base < nb; base += 256) {
        int i = base + tid;
        int v = (i < nb) ? partials[i] : 0;
        sm[tid] = v;
        __syncthreads();
        for (int ofs = 1; ofs < 256; ofs <<= 1) {
            int t = (tid >= ofs) ? sm[tid - ofs] : 0;
            __syncthreads();
            sm[tid] += t;
            __syncthreads();
        }
        int cbase = carry;
        int tot = sm[255];
        if (i < nb) partials[i] = sm[tid] - v + cbase;
        __syncthreads();
        if (tid == 0) carry = cbase + tot;
        __syncthreads();
    }
}

__global__ __launch_bounds__(256) void add_offsets_kernel(
    int* __restrict__ rowptr, const int* __restrict__ partials, int n)
{
    int i = blockIdx.x * 256 + threadIdx.x;
    if (i < n) rowptr[i] += partials[blockIdx.x];
}

__global__ __launch_bounds__(256) void place_kernel(
    const int* __restrict__ src, const int* __restrict__ dst,
    const int* __restrict__ rowptr, int* __restrict__ deg,
    int* __restrict__ csr, int nedges)
{
    int e = blockIdx.x * 256 + threadIdx.x;
    if (e >= nedges) return;
    int d = dst[e];
    int slot = atomicAdd(&deg[d], 1);
    csr[rowptr[d] + slot] = src[e];
}

// ---------- fused MFMA layer ----------
__global__ __launch_bounds__(256) void layer_kernel(
    const bf16* __restrict__ h, const int* __restrict__ rowptr,
    const int* __restrict__ deg, const int* __restrict__ csr,
    const short8* __restrict__ wfG1, const short8* __restrict__ wfG2,
    const float* __restrict__ b1, const float* __restrict__ g1, const float* __restrict__ bt1,
    const float* __restrict__ b2, const float* __restrict__ g2, const float* __restrict__ bt2,
    bf16* __restrict__ out, int nrows)
{
    __shared__ __align__(16) short lds_all[4][1024];   // per wave [16][64] bf16
    int wave = __builtin_amdgcn_readfirstlane(threadIdx.x >> 6);
    int lane = threadIdx.x & 63;
    char* ldsb = (char*)&lds_all[wave][0];
    int r0 = (blockIdx.x * 4 + wave) * 16;

    // ---- gather: z[r] = h[row][lane] + sum_neighbors (lane = feature) ----
    int s[16], c[16], maxc = 0;
#pragma unroll
    for (int r = 0; r < 16; ++r) {
        int row = r0 + r;
        if (row < nrows) { s[r] = rowptr[row]; c[r] = deg[row]; }
        else             { s[r] = 0; c[r] = 0; }
        maxc = max(maxc, c[r]);
    }
    float z[16];
#pragma unroll
    for (int r = 0; r < 16; ++r)
        z[r] = (r0 + r < nrows) ? ldbf(&h[(size_t)(r0 + r) * HH + lane]) : 0.0f;

    for (int j = 0; j < maxc; ++j) {
        float v[16];
#pragma unroll
        for (int r = 0; r < 16; ++r) {
            int jj = min(j, max(c[r] - 1, 0));
            int sn = csr[s[r] + jj];
            sn = min(max(sn, 0), nrows - 1);
            v[r] = ldbf(&h[(size_t)sn * HH + lane]);
        }
#pragma unroll
        for (int r = 0; r < 16; ++r)
            z[r] += (j < c[r]) ? v[r] : 0.0f;
    }

    // ---- z -> LDS bf16 [16][64], XOR-swizzled ----
#pragma unroll
    for (int r = 0; r < 16; ++r)
        *(short*)(ldsb + r * 128 + ((lane * 2) ^ ((r & 7) << 4))) = (short)f2bf(z[r]);
    __syncthreads();

    // ---- GEMM1 ----
    short8 a0, a1;
    {
        int rr = lane & 15;
        a0 = *(const short8*)(ldsb + rr * 128 + (((lane >> 4) * 16) ^ ((rr & 7) << 4)));
        a1 = *(const short8*)(ldsb + rr * 128 + ((64 + (lane >> 4) * 16) ^ ((rr & 7) << 4)));
    }
    f32x4 acc[4];
#pragma unroll
    for (int tile = 0; tile < 4; ++tile) {
        acc[tile] = (f32x4){0.f, 0.f, 0.f, 0.f};
        acc[tile] = __builtin_amdgcn_mfma_f32_16x16x32_bf16(a0, wfG1[(tile * 2 + 0) * 64 + lane], acc[tile], 0, 0, 0);
        acc[tile] = __builtin_amdgcn_mfma_f32_16x16x32_bf16(a1, wfG1[(tile * 2 + 1) * 64 + lane], acc[tile], 0, 0, 0);
    }
    __syncthreads();
    // epilogue1: bn+relu -> LDS t
#pragma unroll
    for (int tile = 0; tile < 4; ++tile) {
        int col = tile * 16 + (lane & 15);
        float sc = g1[col] * BN_RSQRT;
        float sh = fmaf(b1[col], sc, bt1[col]);
#pragma unroll
        for (int q = 0; q < 4; ++q) {
            int row = (lane >> 4) * 4 + q;
            float v = fmaxf(fmaf(acc[tile][q], sc, sh), 0.0f);
            *(short*)(ldsb + row * 128 + ((col * 2) ^ ((row & 7) << 4))) = (short)f2bf(v);
        }
    }
    __syncthreads();

    // ---- GEMM2 ----
    {
        int rr = lane & 15;
        a0 = *(const short8*)(ldsb + rr * 128 + (((lane >> 4) * 16) ^ ((rr & 7) << 4)));
        a1 = *(const short8*)(ldsb + rr * 128 + ((64 + (lane >> 4) * 16) ^ ((rr & 7) << 4)));
    }
#pragma unroll
    for (int tile = 0; tile < 4; ++tile) {
        acc[tile] = (f32x4){0.f, 0.f, 0.f, 0.f};
        acc[tile] = __builtin_amdgcn_mfma_f32_16x16x32_bf16(a0, wfG2[(tile * 2 + 0) * 64 + lane], acc[tile], 0, 0, 0);
        acc[tile] = __builtin_amdgcn_mfma_f32_16x16x32_bf16(a1, wfG2[(tile * 2 + 1) * 64 + lane], acc[tile], 0, 0, 0);
    }
    __syncthreads();
    // epilogue2: bn+relu -> LDS out
#pragma unroll
    for (int tile = 0; tile < 4; ++tile) {
        int col = tile * 16 + (lane & 15);
        float sc = g2[col] * BN_RSQRT;
        float sh = fmaf(b2[col], sc, bt2[col]);
#pragma unroll
        for (int q = 0; q < 4; ++q) {
            int row = (lane >> 4) * 4 + q;
            float v = fmaxf(fmaf(acc[tile][q], sc, sh), 0.0f);
            *(short*)(ldsb + row * 128 + ((col * 2) ^ ((row & 7) << 4))) = (short)f2bf(v);
        }
    }
    __syncthreads();
    // coalesced store
#pragma unroll
    for (int half = 0; half < 2; ++half) {
        int row = (lane >> 3) + half * 8;
        short8 vv = *(const short8*)(ldsb + row * 128 + ((((lane & 7) * 16)) ^ ((row & 7) << 4)));
        int grow = r0 + row;
        if (grow < nrows)
            *(short8*)((char*)out + (size_t)grow * 128 + (lane & 7) * 16) = vv;
    }
}

// ---------- fused final linear + mean-pool partials (VALU) ----------
__global__ __launch_bounds__(256) void poolgemm_kernel(
    const bf16* __restrict__ h, const int* __restrict__ batch,
    const float* __restrict__ Wl1, const float* __restrict__ bl1,
    float* __restrict__ pooled, float* __restrict__ cnt, int nrows)
{
    int wave = __builtin_amdgcn_readfirstlane(threadIdx.x >> 6);
    int lane = threadIdx.x & 63;
    int base = (blockIdx.x * 4 + wave) * 64;
    if (base >= nrows) return;
    int lim = min(base + 64, nrows);

    float acc = 0.0f;
    int curg = -1, runcnt = 0;
    float bias = bl1[lane];

    for (int rb = base; rb < lim; rb += 4) {
        float z[4], t[4];
#pragma unroll
        for (int r = 0; r < 4; ++r) {
            int row = rb + r;
            z[r] = (row < lim) ? ldbf(&h[(size_t)row * HH + lane]) : 0.0f;
            t[r] = bias;
        }
#pragma unroll 8
        for (int k = 0; k < 64; ++k) {
            float w = Wl1[k * HH + lane];
#pragma unroll
            for (int r = 0; r < 4; ++r) t[r] = fmaf(bcast(z[r], k), w, t[r]);
        }
#pragma unroll
        for (int r = 0; r < 4; ++r) {
            int row = rb + r;
            if (row < lim) {
                float hv = fmaxf(t[r], 0.0f);
                int g = batch[row];
                if (g != curg) {
                    if (curg >= 0) {
                        atomicAdd(&pooled[curg * HH + lane], acc);
                        if (lane == 0) atomicAdd(&cnt[curg], (float)runcnt);
                    }
                    curg = g; acc = hv; runcnt = 1;
                } else { acc += hv; runcnt += 1; }
            }
        }
    }
    if (curg >= 0) {
        atomicAdd(&pooled[curg * HH + lane], acc);
        if (lane == 0) atomicAdd(&cnt[curg], (float)runcnt);
    }
}

__global__ __launch_bounds__(64) void head_kernel(
    const float* __restrict__ pooled, const float* __restrict__ cnt,
    const float* __restrict__ Wl2, const float* __restrict__ bl2,
    float* __restrict__ out, int ngraphs)
{
    int gidx = blockIdx.x * 64 + threadIdx.x;
    if (gidx >= ngraphs) return;
    float logits[CC];
#pragma unroll
    for (int c = 0; c < CC; ++c) logits[c] = bl2[c];
    float inv_n = 1.0f / fmaxf(cnt[gidx], 1.0f);
    for (int k = 0; k < HH; ++k) {
        float p = pooled[gidx * HH + k] * inv_n;
#pragma unroll
        for (int c = 0; c < CC; ++c) logits[c] = fmaf(p, Wl2[k * CC + c], logits[c]);
    }
    float m = logits[0];
#pragma unroll
    for (int c = 1; c < CC; ++c) m = fmaxf(m, logits[c]);
    float ssum = 0.0f;
#pragma unroll
    for (int c = 0; c < CC; ++c) { logits[c] = __expf(logits[c] - m); ssum += logits[c]; }
    float inv = 1.0f / ssum;
#pragma unroll
    for (int c = 0; c < CC; ++c) out[gidx * CC + c] = logits[c] * inv;
}

extern "C" void kernel_launch(void* const* d_in, const int* in_sizes, int n_in,
                              void* d_out, int out_size, void* d_ws, size_t ws_size,
                              hipStream_t stream) {
    const float* x      = (const float*)d_in[0];
    const int*   ei     = (const int*)  d_in[1];
    const int*   batch  = (const int*)  d_in[3];
    const float* W0     = (const float*)d_in[4];
    const float* b0     = (const float*)d_in[5];
    const float* convW1 = (const float*)d_in[6];
    const float* convb1 = (const float*)d_in[7];
    const float* convg1 = (const float*)d_in[8];
    const float* convbt1= (const float*)d_in[9];
    const float* convW2 = (const float*)d_in[10];
    const float* convb2 = (const float*)d_in[11];
    const float* convg2 = (const float*)d_in[12];
    const float* convbt2= (const float*)d_in[13];
    const float* Wl1    = (const float*)d_in[14];
    const float* bl1    = (const float*)d_in[15];
    const float* Wl2    = (const float*)d_in[16];
    const float* bl2    = (const float*)d_in[17];

    const int N = in_sizes[0] / FF;
    const int E = in_sizes[1] / 2;
    const int G = out_size / CC;

    const int* src = ei;
    const int* dst = ei + E;

    size_t off = 0;
    auto take = [&](size_t bytes) { size_t p = off; off = (off + bytes + 255) & ~255ULL; return p; };
    int NB = (N + 255) / 256;
    int EB = (E + 255) / 256;
    size_t o_rowptr = take((size_t)N * 4);
    size_t o_deg    = take((size_t)N * 4);
    size_t o_csr    = take((size_t)(E > NB ? E : NB) * 4 + 256);
    size_t o_pooled = take((size_t)G * HH * 4);
    size_t o_cnt    = take((size_t)G * 4);
    size_t o_wfrag  = take((size_t)5120 * 8 * 2);
    size_t o_hA     = take((size_t)N * HH * 2);
    size_t o_hB     = take((size_t)N * HH * 2);

    char* base = (char*)d_ws;
    int*    rowptr = (int*)(base + o_rowptr);
    int*    deg    = (int*)(base + o_deg);
    int*    csr    = (int*)(base + o_csr);
    float*  pooled = (float*)(base + o_pooled);
    float*  cnt    = (float*)(base + o_cnt);
    short*  wfrag  = (short*)(base + o_wfrag);
    short8* wf8    = (short8*)wfrag;
    bf16*   hA     = (bf16*)(base + o_hA);
    bf16*   hB     = (bf16*)(base + o_hB);

    int tile_blocks = (N + 63) / 64;     // 4 waves x 16 rows
    int pool_blocks = ((N + 63) / 64 + 3) / 4;

    // weight fragment packing
    pack_weights_kernel<<<20, 256, 0, stream>>>(W0, convW1, convW2, wfrag);

    // CSR build
    hipMemsetAsync(deg, 0, (size_t)N * sizeof(int), stream);
    hist_kernel<<<EB, 256, 0, stream>>>(dst, deg, E);
    scan_block_kernel<<<NB, 256, 0, stream>>>(deg, rowptr, csr /*partials*/, N);
    scan_partials_kernel<<<1, 256, 0, stream>>>(csr, NB);
    add_offsets_kernel<<<NB, 256, 0, stream>>>(rowptr, csr, N);
    hipMemsetAsync(deg, 0, (size_t)N * sizeof(int), stream);
    place_kernel<<<EB, 256, 0, stream>>>(src, dst, rowptr, deg, csr, E);

    // lin0
    lin0_kernel<<<tile_blocks, 256, 0, stream>>>(x, wf8, b0, hA, N);

    // layers (ping-pong)
    const bf16* hin = hA; bf16* hout = hB;
    for (int l = 0; l < LL; ++l) {
        const short8* wfG1 = wf8 + 1024 + (size_t)(l * 2 + 0) * 512;
        const short8* wfG2 = wf8 + 1024 + (size_t)(l * 2 + 1) * 512;
        layer_kernel<<<tile_blocks, 256, 0, stream>>>(
            hin, rowptr, deg, csr, wfG1, wfG2,
            convb1 + l * HH, convg1 + l * HH, convbt1 + l * HH,
            convb2 + l * HH, convg2 + l * HH, convbt2 + l * HH,
            hout, N);
        bf16* tswap = (bf16*)hin; hin = hout; hout = tswap;
    }

    // final linear + pool + head
    hipMemsetAsync(pooled, 0, (size_t)G * HH * sizeof(float), stream);
    hipMemsetAsync(cnt, 0, (size_t)G * sizeof(float), stream);
    poolgemm_kernel<<<pool_blocks, 256, 0, stream>>>(hin, batch, Wl1, bl1, pooled, cnt, N);
    head_kernel<<<(G + 63) / 64, 64, 0, stream>>>(pooled, cnt, Wl2, bl2, (float*)d_out, G);
}

// Round 5
// 421.977 us; speedup vs baseline: 4.4350x; 1.1651x over previous
//
#include <hip/hip_runtime.h>
#include <hip/hip_bf16.h>

#define HH 64
#define FF 128
#define CC 10
#define LL 4
#define BN_RSQRT 0.9999950000374997f   // 1/sqrt(1+1e-5)

typedef __hip_bfloat16 bf16;
using short8 = __attribute__((ext_vector_type(8))) short;
using f32x4  = __attribute__((ext_vector_type(4))) float;

__device__ __forceinline__ float ldbf(const bf16* p) {
    return __uint_as_float(((unsigned)*(const unsigned short*)p) << 16);
}
__device__ __forceinline__ float us2f(unsigned short u) {
    return __uint_as_float(((unsigned)u) << 16);
}
// RNE f32->bf16 bits (finite inputs)
__device__ __forceinline__ unsigned short f2bf(float v) {
    unsigned u = __float_as_uint(v);
    return (unsigned short)((u + 0x7FFFu + ((u >> 16) & 1u)) >> 16);
}
__device__ __forceinline__ float bcast(float v, int k) {
    return __uint_as_float(__builtin_amdgcn_readlane(__float_as_uint(v), k));
}

// ---------- weight fragment packing ----------
// B-frag layout for mfma_f32_16x16x32_bf16: lane l holds B[k][n] with
// n = tile*16 + (l&15), k = kc*32 + (l>>4)*8 + e, e=0..7.
// wf8[0..1023]             : W0   (128x64, 16 frags x 64 lanes)
// wf8[1024 + m*512 + ...]  : conv m = layer*2+g (64x64, 8 frags x 64)
// wf8[5120..5631]          : Wl1  (64x64)
__global__ __launch_bounds__(256) void pack_weights_kernel(
    const float* __restrict__ W0, const float* __restrict__ convW1,
    const float* __restrict__ convW2, const float* __restrict__ Wl1,
    short* __restrict__ wf)
{
    int t = blockIdx.x * 256 + threadIdx.x;
    if (t >= 5632) return;
    const float* W;
    int l, tile, kc, out_idx;
    if (t < 1024) {
        int local = t; int fi = local >> 6; l = local & 63;
        tile = fi >> 2; kc = fi & 3;
        W = W0; out_idx = local;
    } else if (t < 5120) {
        int t2 = t - 1024;
        int m = t2 >> 9;
        int local = t2 & 511;
        int fi = local >> 6; l = local & 63;
        tile = fi >> 1; kc = fi & 1;
        int layer = m >> 1, g = m & 1;
        W = (g ? convW2 : convW1) + (size_t)layer * HH * HH;
        out_idx = 1024 + m * 512 + local;
    } else {
        int local = t - 5120;
        int fi = local >> 6; l = local & 63;
        tile = fi >> 1; kc = fi & 1;
        W = Wl1; out_idx = 5120 + local;
    }
    int k0 = kc * 32 + (l >> 4) * 8;
    int n = tile * 16 + (l & 15);
#pragma unroll
    for (int e = 0; e < 8; ++e)
        wf[out_idx * 8 + e] = (short)f2bf(W[(k0 + e) * HH + n]);
}

// ---------- lin0 (MFMA): h = relu(x @ W0 + b0) ----------
__global__ __launch_bounds__(256) void lin0_kernel(
    const float* __restrict__ x, const short8* __restrict__ wf0,
    const float* __restrict__ b0, bf16* __restrict__ h, int nrows)
{
    __shared__ __align__(16) short lds_all[4][2048];   // per wave [16][128] bf16
    int wave = __builtin_amdgcn_readfirstlane(threadIdx.x >> 6);
    int lane = threadIdx.x & 63;
    char* ldsb = (char*)&lds_all[wave][0];
    int r0 = (blockIdx.x * 4 + wave) * 16;

#pragma unroll
    for (int r = 0; r < 16; ++r) {
        int row = r0 + r;
        float2 xv = make_float2(0.f, 0.f);
        if (row < nrows) xv = *(const float2*)(x + (size_t)row * FF + lane * 2);
        unsigned pk = (unsigned)f2bf(xv.x) | ((unsigned)f2bf(xv.y) << 16);
        *(int*)(ldsb + r * 256 + ((lane * 4) ^ ((r & 7) << 4))) = pk;
    }
    __syncthreads();

    short8 a[4];
#pragma unroll
    for (int kc = 0; kc < 4; ++kc) {
        int rr = lane & 15;
        a[kc] = *(const short8*)(ldsb + rr * 256 + (((kc * 64 + (lane >> 4) * 16)) ^ ((rr & 7) << 4)));
    }
    f32x4 acc[4];
#pragma unroll
    for (int tile = 0; tile < 4; ++tile) {
        acc[tile] = (f32x4){0.f, 0.f, 0.f, 0.f};
#pragma unroll
        for (int kc = 0; kc < 4; ++kc) {
            short8 b = wf0[(tile * 4 + kc) * 64 + lane];
            acc[tile] = __builtin_amdgcn_mfma_f32_16x16x32_bf16(a[kc], b, acc[tile], 0, 0, 0);
        }
    }
    __syncthreads();
#pragma unroll
    for (int tile = 0; tile < 4; ++tile) {
        int col = tile * 16 + (lane & 15);
        float bia = b0[col];
#pragma unroll
        for (int q = 0; q < 4; ++q) {
            int row = (lane >> 4) * 4 + q;
            float v = fmaxf(acc[tile][q] + bia, 0.0f);
            *(short*)(ldsb + row * 256 + ((col * 2) ^ ((row & 7) << 4))) = (short)f2bf(v);
        }
    }
    __syncthreads();
#pragma unroll
    for (int half = 0; half < 2; ++half) {
        int row = (lane >> 3) + half * 8;
        short8 vv = *(const short8*)(ldsb + row * 256 + ((((lane & 7) * 16)) ^ ((row & 7) << 4)));
        int grow = r0 + row;
        if (grow < nrows)
            *(short8*)((char*)h + (size_t)grow * 128 + (lane & 7) * 16) = vv;
    }
}

// ---------- CSR build ----------
__global__ __launch_bounds__(256) void hist_kernel(
    const int* __restrict__ dst, int* __restrict__ deg, int nedges)
{
    int e = blockIdx.x * 256 + threadIdx.x;
    if (e < nedges) atomicAdd(&deg[dst[e]], 1);
}

__global__ __launch_bounds__(256) void scan_block_kernel(
    const int* __restrict__ deg, int* __restrict__ rowptr,
    int* __restrict__ partials, int n)
{
    __shared__ int sm[256];
    int tid = threadIdx.x;
    int i = blockIdx.x * 256 + tid;
    int v = (i < n) ? deg[i] : 0;
    sm[tid] = v;
    __syncthreads();
    for (int ofs = 1; ofs < 256; ofs <<= 1) {
        int t = (tid >= ofs) ? sm[tid - ofs] : 0;
        __syncthreads();
        sm[tid] += t;
        __syncthreads();
    }
    if (i < n) rowptr[i] = sm[tid] - v;
    if (tid == 255) partials[blockIdx.x] = sm[255];
}

__global__ __launch_bounds__(256) void scan_partials_kernel(int* partials, int nb)
{
    __shared__ int sm[256];
    __shared__ int carry;
    int tid = threadIdx.x;
    if (tid == 0) carry = 0;
    __syncthreads();
    for (int base = 0; base < nb; base += 256) {
        int i = base + tid;
        int v = (i < nb) ? partials[i] : 0;
        sm[tid] = v;
        __syncthreads();
        for (int ofs = 1; ofs < 256; ofs <<= 1) {
            int t = (tid >= ofs) ? sm[tid - ofs] : 0;
            __syncthreads();
            sm[tid] += t;
            __syncthreads();
        }
        int cbase = carry;
        int tot = sm[255];
        if (i < nb) partials[i] = sm[tid] - v + cbase;
        __syncthreads();
        if (tid == 0) carry = cbase + tot;
        __syncthreads();
    }
}

__global__ __launch_bounds__(256) void add_offsets_kernel(
    int* __restrict__ rowptr, const int* __restrict__ partials, int n)
{
    int i = blockIdx.x * 256 + threadIdx.x;
    if (i < n) rowptr[i] += partials[blockIdx.x];
}

// 4 strided edges per thread -> 4 independent atomic->store chains in flight
__global__ __launch_bounds__(256) void place_kernel(
    const int* __restrict__ src, const int* __restrict__ dst,
    const int* __restrict__ rowptr, int* __restrict__ deg,
    int* __restrict__ csr, int nedges, int stride)
{
    int t = blockIdx.x * 256 + threadIdx.x;
    int e[4], d[4], slot[4];
    bool ok[4];
#pragma unroll
    for (int i = 0; i < 4; ++i) {
        e[i] = t + i * stride;
        ok[i] = e[i] < nedges;
        d[i] = ok[i] ? dst[e[i]] : 0;
    }
#pragma unroll
    for (int i = 0; i < 4; ++i)
        slot[i] = ok[i] ? atomicAdd(&deg[d[i]], 1) : 0;
#pragma unroll
    for (int i = 0; i < 4; ++i)
        if (ok[i]) csr[rowptr[d[i]] + slot[i]] = src[e[i]];
}

// ---------- fused MFMA layer (FINAL adds 3rd GEMM + in-kernel pooling) ----------
template <int FINAL>
__global__ __launch_bounds__(256) void layer_kernel(
    const bf16* __restrict__ h, const int* __restrict__ rowptr,
    const int* __restrict__ deg, const int* __restrict__ csr,
    const short8* __restrict__ wfG1, const short8* __restrict__ wfG2,
    const float* __restrict__ b1, const float* __restrict__ g1, const float* __restrict__ bt1,
    const float* __restrict__ b2, const float* __restrict__ g2, const float* __restrict__ bt2,
    bf16* __restrict__ out, int nrows,
    const short8* __restrict__ wfL1, const float* __restrict__ bl1,
    const int* __restrict__ batch, float* __restrict__ pooled, float* __restrict__ cnt)
{
    __shared__ __align__(16) short lds_all[4][1024];   // per wave [16][64] bf16
    int wave = __builtin_amdgcn_readfirstlane(threadIdx.x >> 6);
    int lane = threadIdx.x & 63;
    char* ldsb = (char*)&lds_all[wave][0];
    int r0 = (blockIdx.x * 4 + wave) * 16;

    // ---- gather ----
    int s[16], c[16], maxc = 0;
#pragma unroll
    for (int r = 0; r < 16; ++r) {
        int row = r0 + r;
        if (row < nrows) { s[r] = rowptr[row]; c[r] = deg[row]; }
        else             { s[r] = 0; c[r] = 0; }
        maxc = max(maxc, c[r]);
    }
    float z[16];
#pragma unroll
    for (int r = 0; r < 16; ++r)
        z[r] = (r0 + r < nrows) ? ldbf(&h[(size_t)(r0 + r) * HH + lane]) : 0.0f;

    for (int j = 0; j < maxc; ++j) {
        float v[16];
#pragma unroll
        for (int r = 0; r < 16; ++r) {
            int jj = min(j, max(c[r] - 1, 0));
            int sn = csr[s[r] + jj];
            sn = min(max(sn, 0), nrows - 1);
            v[r] = ldbf(&h[(size_t)sn * HH + lane]);
        }
#pragma unroll
        for (int r = 0; r < 16; ++r)
            z[r] += (j < c[r]) ? v[r] : 0.0f;
    }

#pragma unroll
    for (int r = 0; r < 16; ++r)
        *(short*)(ldsb + r * 128 + ((lane * 2) ^ ((r & 7) << 4))) = (short)f2bf(z[r]);
    __syncthreads();

    short8 a0, a1;
    f32x4 acc[4];
    // ---- GEMM1 + BN + ReLU ----
    {
        int rr = lane & 15;
        a0 = *(const short8*)(ldsb + rr * 128 + (((lane >> 4) * 16) ^ ((rr & 7) << 4)));
        a1 = *(const short8*)(ldsb + rr * 128 + ((64 + (lane >> 4) * 16) ^ ((rr & 7) << 4)));
    }
#pragma unroll
    for (int tile = 0; tile < 4; ++tile) {
        acc[tile] = (f32x4){0.f, 0.f, 0.f, 0.f};
        acc[tile] = __builtin_amdgcn_mfma_f32_16x16x32_bf16(a0, wfG1[(tile * 2 + 0) * 64 + lane], acc[tile], 0, 0, 0);
        acc[tile] = __builtin_amdgcn_mfma_f32_16x16x32_bf16(a1, wfG1[(tile * 2 + 1) * 64 + lane], acc[tile], 0, 0, 0);
    }
    __syncthreads();
#pragma unroll
    for (int tile = 0; tile < 4; ++tile) {
        int col = tile * 16 + (lane & 15);
        float sc = g1[col] * BN_RSQRT;
        float sh = fmaf(b1[col], sc, bt1[col]);
#pragma unroll
        for (int q = 0; q < 4; ++q) {
            int row = (lane >> 4) * 4 + q;
            float v = fmaxf(fmaf(acc[tile][q], sc, sh), 0.0f);
            *(short*)(ldsb + row * 128 + ((col * 2) ^ ((row & 7) << 4))) = (short)f2bf(v);
        }
    }
    __syncthreads();

    // ---- GEMM2 + BN + ReLU ----
    {
        int rr = lane & 15;
        a0 = *(const short8*)(ldsb + rr * 128 + (((lane >> 4) * 16) ^ ((rr & 7) << 4)));
        a1 = *(const short8*)(ldsb + rr * 128 + ((64 + (lane >> 4) * 16) ^ ((rr & 7) << 4)));
    }
#pragma unroll
    for (int tile = 0; tile < 4; ++tile) {
        acc[tile] = (f32x4){0.f, 0.f, 0.f, 0.f};
        acc[tile] = __builtin_amdgcn_mfma_f32_16x16x32_bf16(a0, wfG2[(tile * 2 + 0) * 64 + lane], acc[tile], 0, 0, 0);
        acc[tile] = __builtin_amdgcn_mfma_f32_16x16x32_bf16(a1, wfG2[(tile * 2 + 1) * 64 + lane], acc[tile], 0, 0, 0);
    }
    __syncthreads();
#pragma unroll
    for (int tile = 0; tile < 4; ++tile) {
        int col = tile * 16 + (lane & 15);
        float sc = g2[col] * BN_RSQRT;
        float sh = fmaf(b2[col], sc, bt2[col]);
#pragma unroll
        for (int q = 0; q < 4; ++q) {
            int row = (lane >> 4) * 4 + q;
            float v = fmaxf(fmaf(acc[tile][q], sc, sh), 0.0f);
            *(short*)(ldsb + row * 128 + ((col * 2) ^ ((row & 7) << 4))) = (short)f2bf(v);
        }
    }
    __syncthreads();

    if (FINAL == 0) {
        // coalesced store of layer output
#pragma unroll
        for (int half = 0; half < 2; ++half) {
            int row = (lane >> 3) + half * 8;
            short8 vv = *(const short8*)(ldsb + row * 128 + ((((lane & 7) * 16)) ^ ((row & 7) << 4)));
            int grow = r0 + row;
            if (grow < nrows)
                *(short8*)((char*)out + (size_t)grow * 128 + (lane & 7) * 16) = vv;
        }
    } else {
        // ---- GEMM3: relu(h4 @ Wl1 + bl1) ----
        {
            int rr = lane & 15;
            a0 = *(const short8*)(ldsb + rr * 128 + (((lane >> 4) * 16) ^ ((rr & 7) << 4)));
            a1 = *(const short8*)(ldsb + rr * 128 + ((64 + (lane >> 4) * 16) ^ ((rr & 7) << 4)));
        }
#pragma unroll
        for (int tile = 0; tile < 4; ++tile) {
            acc[tile] = (f32x4){0.f, 0.f, 0.f, 0.f};
            acc[tile] = __builtin_amdgcn_mfma_f32_16x16x32_bf16(a0, wfL1[(tile * 2 + 0) * 64 + lane], acc[tile], 0, 0, 0);
            acc[tile] = __builtin_amdgcn_mfma_f32_16x16x32_bf16(a1, wfL1[(tile * 2 + 1) * 64 + lane], acc[tile], 0, 0, 0);
        }
        __syncthreads();
#pragma unroll
        for (int tile = 0; tile < 4; ++tile) {
            int col = tile * 16 + (lane & 15);
            float bia = bl1[col];
#pragma unroll
            for (int q = 0; q < 4; ++q) {
                int row = (lane >> 4) * 4 + q;
                float v = fmaxf(acc[tile][q] + bia, 0.0f);
                *(short*)(ldsb + row * 128 + ((col * 2) ^ ((row & 7) << 4))) = (short)f2bf(v);
            }
        }
        __syncthreads();
        // ---- in-kernel mean-pool partials (run-length flush, batch sorted) ----
        float pacc = 0.0f;
        int curg = -1, rc = 0;
        for (int r = 0; r < 16; ++r) {
            int row = r0 + r;
            if (row >= nrows) break;
            float v = us2f(*(const unsigned short*)(ldsb + r * 128 + ((lane * 2) ^ ((r & 7) << 4))));
            int g = batch[row];
            if (g != curg) {
                if (curg >= 0) {
                    atomicAdd(&pooled[curg * HH + lane], pacc);
                    if (lane == 0) atomicAdd(&cnt[curg], (float)rc);
                }
                curg = g; pacc = v; rc = 1;
            } else { pacc += v; rc += 1; }
        }
        if (curg >= 0) {
            atomicAdd(&pooled[curg * HH + lane], pacc);
            if (lane == 0) atomicAdd(&cnt[curg], (float)rc);
        }
    }
}

__global__ __launch_bounds__(64) void head_kernel(
    const float* __restrict__ pooled, const float* __restrict__ cnt,
    const float* __restrict__ Wl2, const float* __restrict__ bl2,
    float* __restrict__ out, int ngraphs)
{
    int gidx = blockIdx.x * 64 + threadIdx.x;
    if (gidx >= ngraphs) return;
    float logits[CC];
#pragma unroll
    for (int c = 0; c < CC; ++c) logits[c] = bl2[c];
    float inv_n = 1.0f / fmaxf(cnt[gidx], 1.0f);
    for (int k = 0; k < HH; ++k) {
        float p = pooled[gidx * HH + k] * inv_n;
#pragma unroll
        for (int c = 0; c < CC; ++c) logits[c] = fmaf(p, Wl2[k * CC + c], logits[c]);
    }
    float m = logits[0];
#pragma unroll
    for (int c = 1; c < CC; ++c) m = fmaxf(m, logits[c]);
    float ssum = 0.0f;
#pragma unroll
    for (int c = 0; c < CC; ++c) { logits[c] = __expf(logits[c] - m); ssum += logits[c]; }
    float inv = 1.0f / ssum;
#pragma unroll
    for (int c = 0; c < CC; ++c) out[gidx * CC + c] = logits[c] * inv;
}

extern "C" void kernel_launch(void* const* d_in, const int* in_sizes, int n_in,
                              void* d_out, int out_size, void* d_ws, size_t ws_size,
                              hipStream_t stream) {
    const float* x      = (const float*)d_in[0];
    const int*   ei     = (const int*)  d_in[1];
    const int*   batch  = (const int*)  d_in[3];
    const float* W0     = (const float*)d_in[4];
    const float* b0     = (const float*)d_in[5];
    const float* convW1 = (const float*)d_in[6];
    const float* convb1 = (const float*)d_in[7];
    const float* convg1 = (const float*)d_in[8];
    const float* convbt1= (const float*)d_in[9];
    const float* convW2 = (const float*)d_in[10];
    const float* convb2 = (const float*)d_in[11];
    const float* convg2 = (const float*)d_in[12];
    const float* convbt2= (const float*)d_in[13];
    const float* Wl1    = (const float*)d_in[14];
    const float* bl1    = (const float*)d_in[15];
    const float* Wl2    = (const float*)d_in[16];
    const float* bl2    = (const float*)d_in[17];

    const int N = in_sizes[0] / FF;
    const int E = in_sizes[1] / 2;
    const int G = out_size / CC;

    const int* src = ei;
    const int* dst = ei + E;

    size_t off = 0;
    auto take = [&](size_t bytes) { size_t p = off; off = (off + bytes + 255) & ~255ULL; return p; };
    int NB = (N + 255) / 256;
    int EB = (E + 255) / 256;
    size_t o_rowptr = take((size_t)N * 4);
    size_t o_deg    = take((size_t)N * 4);
    size_t o_csr    = take((size_t)(E > NB ? E : NB) * 4 + 256);
    size_t o_pooled = take((size_t)G * HH * 4);
    size_t o_cnt    = take((size_t)G * 4);
    size_t o_wfrag  = take((size_t)5632 * 8 * 2);
    size_t o_hA     = take((size_t)N * HH * 2);
    size_t o_hB     = take((size_t)N * HH * 2);

    char* base = (char*)d_ws;
    int*    rowptr = (int*)(base + o_rowptr);
    int*    deg    = (int*)(base + o_deg);
    int*    csr    = (int*)(base + o_csr);
    float*  pooled = (float*)(base + o_pooled);
    float*  cnt    = (float*)(base + o_cnt);
    short*  wfrag  = (short*)(base + o_wfrag);
    short8* wf8    = (short8*)wfrag;
    bf16*   hA     = (bf16*)(base + o_hA);
    bf16*   hB     = (bf16*)(base + o_hB);

    int tile_blocks = (N + 63) / 64;     // 4 waves x 16 rows

    // weight fragment packing
    pack_weights_kernel<<<22, 256, 0, stream>>>(W0, convW1, convW2, Wl1, wfrag);

    // CSR build
    hipMemsetAsync(deg, 0, (size_t)N * sizeof(int), stream);
    hist_kernel<<<EB, 256, 0, stream>>>(dst, deg, E);
    scan_block_kernel<<<NB, 256, 0, stream>>>(deg, rowptr, csr /*partials*/, N);
    scan_partials_kernel<<<1, 256, 0, stream>>>(csr, NB);
    add_offsets_kernel<<<NB, 256, 0, stream>>>(rowptr, csr, N);
    hipMemsetAsync(deg, 0, (size_t)N * sizeof(int), stream);
    {
        int stride = ((E + 3) / 4 + 255) & ~255;
        place_kernel<<<stride / 256, 256, 0, stream>>>(src, dst, rowptr, deg, csr, E, stride);
    }

    // lin0
    lin0_kernel<<<tile_blocks, 256, 0, stream>>>(x, wf8, b0, hA, N);

    // pooled/cnt init (before final fused layer)
    hipMemsetAsync(pooled, 0, (size_t)G * HH * sizeof(float), stream);
    hipMemsetAsync(cnt, 0, (size_t)G * sizeof(float), stream);

    // layers (ping-pong); last layer fuses final linear + pooling
    const bf16* hin = hA; bf16* hout = hB;
    const short8* wfL1 = wf8 + 5120;
    for (int l = 0; l < LL; ++l) {
        const short8* wfG1 = wf8 + 1024 + (size_t)(l * 2 + 0) * 512;
        const short8* wfG2 = wf8 + 1024 + (size_t)(l * 2 + 1) * 512;
        if (l < LL - 1) {
            layer_kernel<0><<<tile_blocks, 256, 0, stream>>>(
                hin, rowptr, deg, csr, wfG1, wfG2,
                convb1 + l * HH, convg1 + l * HH, convbt1 + l * HH,
                convb2 + l * HH, convg2 + l * HH, convbt2 + l * HH,
                hout, N, nullptr, nullptr, nullptr, nullptr, nullptr);
        } else {
            layer_kernel<1><<<tile_blocks, 256, 0, stream>>>(
                hin, rowptr, deg, csr, wfG1, wfG2,
                convb1 + l * HH, convg1 + l * HH, convbt1 + l * HH,
                convb2 + l * HH, convg2 + l * HH, convbt2 + l * HH,
                nullptr, N, wfL1, bl1, batch, pooled, cnt);
        }
        bf16* tswap = (bf16*)hin; hin = hout; hout = tswap;
    }

    head_kernel<<<(G + 63) / 64, 64, 0, stream>>>(pooled, cnt, Wl2, bl2, (float*)d_out, G);
}

// Round 6
// 371.466 us; speedup vs baseline: 5.0381x; 1.1360x over previous
//
#include <hip/hip_runtime.h>
#include <hip/hip_bf16.h>

#define HH 64
#define FF 128
#define CC 10
#define LL 4
#define BN_RSQRT 0.9999950000374997f   // 1/sqrt(1+1e-5)

typedef __hip_bfloat16 bf16;
using short8 = __attribute__((ext_vector_type(8))) short;
using f32x4  = __attribute__((ext_vector_type(4))) float;

__device__ __forceinline__ float ldbf(const bf16* p) {
    return __uint_as_float(((unsigned)*(const unsigned short*)p) << 16);
}
__device__ __forceinline__ float us2f(unsigned short u) {
    return __uint_as_float(((unsigned)u) << 16);
}
// RNE f32->bf16 bits (finite inputs)
__device__ __forceinline__ unsigned short f2bf(float v) {
    unsigned u = __float_as_uint(v);
    return (unsigned short)((u + 0x7FFFu + ((u >> 16) & 1u)) >> 16);
}

// ---------- weight fragment packing ----------
// B-frag layout for mfma_f32_16x16x32_bf16: lane l holds B[k][n] with
// n = tile*16 + (l&15), k = kc*32 + (l>>4)*8 + e, e=0..7.
// wf8[0..1023]             : W0   (128x64, 16 frags x 64 lanes)
// wf8[1024 + m*512 + ...]  : conv m = layer*2+g (64x64, 8 frags x 64)
// wf8[5120..5631]          : Wl1  (64x64)
__global__ __launch_bounds__(256) void pack_weights_kernel(
    const float* __restrict__ W0, const float* __restrict__ convW1,
    const float* __restrict__ convW2, const float* __restrict__ Wl1,
    short* __restrict__ wf)
{
    int t = blockIdx.x * 256 + threadIdx.x;
    if (t >= 5632) return;
    const float* W;
    int l, tile, kc, out_idx;
    if (t < 1024) {
        int local = t; int fi = local >> 6; l = local & 63;
        tile = fi >> 2; kc = fi & 3;
        W = W0; out_idx = local;
    } else if (t < 5120) {
        int t2 = t - 1024;
        int m = t2 >> 9;
        int local = t2 & 511;
        int fi = local >> 6; l = local & 63;
        tile = fi >> 1; kc = fi & 1;
        int layer = m >> 1, g = m & 1;
        W = (g ? convW2 : convW1) + (size_t)layer * HH * HH;
        out_idx = 1024 + m * 512 + local;
    } else {
        int local = t - 5120;
        int fi = local >> 6; l = local & 63;
        tile = fi >> 1; kc = fi & 1;
        W = Wl1; out_idx = 5120 + local;
    }
    int k0 = kc * 32 + (l >> 4) * 8;
    int n = tile * 16 + (l & 15);
#pragma unroll
    for (int e = 0; e < 8; ++e)
        wf[out_idx * 8 + e] = (short)f2bf(W[(k0 + e) * HH + n]);
}

// ---------- lin0 (MFMA): h = relu(x @ W0 + b0) ----------
__global__ __launch_bounds__(256) void lin0_kernel(
    const float* __restrict__ x, const short8* __restrict__ wf0,
    const float* __restrict__ b0, bf16* __restrict__ h, int nrows)
{
    __shared__ __align__(16) short lds_all[4][2048];   // per wave [16][128] bf16
    int wave = __builtin_amdgcn_readfirstlane(threadIdx.x >> 6);
    int lane = threadIdx.x & 63;
    char* ldsb = (char*)&lds_all[wave][0];
    int r0 = (blockIdx.x * 4 + wave) * 16;

#pragma unroll
    for (int r = 0; r < 16; ++r) {
        int row = r0 + r;
        float2 xv = make_float2(0.f, 0.f);
        if (row < nrows) xv = *(const float2*)(x + (size_t)row * FF + lane * 2);
        unsigned pk = (unsigned)f2bf(xv.x) | ((unsigned)f2bf(xv.y) << 16);
        *(int*)(ldsb + r * 256 + ((lane * 4) ^ ((r & 7) << 4))) = pk;
    }
    __syncthreads();

    short8 a[4];
#pragma unroll
    for (int kc = 0; kc < 4; ++kc) {
        int rr = lane & 15;
        a[kc] = *(const short8*)(ldsb + rr * 256 + (((kc * 64 + (lane >> 4) * 16)) ^ ((rr & 7) << 4)));
    }
    f32x4 acc[4];
#pragma unroll
    for (int tile = 0; tile < 4; ++tile) {
        acc[tile] = (f32x4){0.f, 0.f, 0.f, 0.f};
#pragma unroll
        for (int kc = 0; kc < 4; ++kc) {
            short8 b = wf0[(tile * 4 + kc) * 64 + lane];
            acc[tile] = __builtin_amdgcn_mfma_f32_16x16x32_bf16(a[kc], b, acc[tile], 0, 0, 0);
        }
    }
    __syncthreads();
#pragma unroll
    for (int tile = 0; tile < 4; ++tile) {
        int col = tile * 16 + (lane & 15);
        float bia = b0[col];
#pragma unroll
        for (int q = 0; q < 4; ++q) {
            int row = (lane >> 4) * 4 + q;
            float v = fmaxf(acc[tile][q] + bia, 0.0f);
            *(short*)(ldsb + row * 256 + ((col * 2) ^ ((row & 7) << 4))) = (short)f2bf(v);
        }
    }
    __syncthreads();
#pragma unroll
    for (int half = 0; half < 2; ++half) {
        int row = (lane >> 3) + half * 8;
        short8 vv = *(const short8*)(ldsb + row * 256 + ((((lane & 7) * 16)) ^ ((row & 7) << 4)));
        int grow = r0 + row;
        if (grow < nrows)
            *(short8*)((char*)h + (size_t)grow * 128 + (lane & 7) * 16) = vv;
    }
}

// ---------- CSR build ----------
__global__ __launch_bounds__(256) void hist_kernel(
    const int* __restrict__ dst, int* __restrict__ deg, int nedges)
{
    int e = blockIdx.x * 256 + threadIdx.x;
    if (e < nedges) atomicAdd(&deg[dst[e]], 1);
}

__global__ __launch_bounds__(256) void scan_block_kernel(
    const int* __restrict__ deg, int* __restrict__ rowptr,
    int* __restrict__ partials, int n)
{
    __shared__ int sm[256];
    int tid = threadIdx.x;
    int i = blockIdx.x * 256 + tid;
    int v = (i < n) ? deg[i] : 0;
    sm[tid] = v;
    __syncthreads();
    for (int ofs = 1; ofs < 256; ofs <<= 1) {
        int t = (tid >= ofs) ? sm[tid - ofs] : 0;
        __syncthreads();
        sm[tid] += t;
        __syncthreads();
    }
    if (i < n) rowptr[i] = sm[tid] - v;
    if (tid == 255) partials[blockIdx.x] = sm[255];
}

__global__ __launch_bounds__(256) void scan_partials_kernel(int* partials, int nb)
{
    __shared__ int sm[256];
    __shared__ int carry;
    int tid = threadIdx.x;
    if (tid == 0) carry = 0;
    __syncthreads();
    for (int base = 0; base < nb; base += 256) {
        int i = base + tid;
        int v = (i < nb) ? partials[i] : 0;
        sm[tid] = v;
        __syncthreads();
        for (int ofs = 1; ofs < 256; ofs <<= 1) {
            int t = (tid >= ofs) ? sm[tid - ofs] : 0;
            __syncthreads();
            sm[tid] += t;
            __syncthreads();
        }
        int cbase = carry;
        int tot = sm[255];
        if (i < nb) partials[i] = sm[tid] - v + cbase;
        __syncthreads();
        if (tid == 0) carry = cbase + tot;
        __syncthreads();
    }
}

__global__ __launch_bounds__(256) void add_offsets_kernel(
    int* __restrict__ rowptr, const int* __restrict__ partials, int n)
{
    int i = blockIdx.x * 256 + threadIdx.x;
    if (i < n) rowptr[i] += partials[blockIdx.x];
}

// 4 strided edges per thread -> 4 independent atomic->store chains in flight
__global__ __launch_bounds__(256) void place_kernel(
    const int* __restrict__ src, const int* __restrict__ dst,
    const int* __restrict__ rowptr, int* __restrict__ deg,
    int* __restrict__ csr, int nedges, int stride)
{
    int t = blockIdx.x * 256 + threadIdx.x;
    int e[4], d[4], slot[4];
    bool ok[4];
#pragma unroll
    for (int i = 0; i < 4; ++i) {
        e[i] = t + i * stride;
        ok[i] = e[i] < nedges;
        d[i] = ok[i] ? dst[e[i]] : 0;
    }
#pragma unroll
    for (int i = 0; i < 4; ++i)
        slot[i] = ok[i] ? atomicAdd(&deg[d[i]], 1) : 0;
#pragma unroll
    for (int i = 0; i < 4; ++i)
        if (ok[i]) csr[rowptr[d[i]] + slot[i]] = src[e[i]];
}

// ---------- fused MFMA layer (FINAL adds 3rd GEMM + in-kernel pooling) ----------
template <int FINAL>
__global__ __launch_bounds__(256) void layer_kernel(
    const bf16* __restrict__ h, const int* __restrict__ rowptr,
    const int* __restrict__ deg, const int* __restrict__ csr,
    const short8* __restrict__ wfG1, const short8* __restrict__ wfG2,
    const float* __restrict__ b1, const float* __restrict__ g1, const float* __restrict__ bt1,
    const float* __restrict__ b2, const float* __restrict__ g2, const float* __restrict__ bt2,
    bf16* __restrict__ out, int nrows,
    const short8* __restrict__ wfL1, const float* __restrict__ bl1,
    const int* __restrict__ batch, float* __restrict__ pooled, float* __restrict__ cnt)
{
    __shared__ __align__(16) short lds_all[4][1024];   // per wave [16][64] bf16
    int wave = __builtin_amdgcn_readfirstlane(threadIdx.x >> 6);
    int lane = threadIdx.x & 63;
    char* ldsb = (char*)&lds_all[wave][0];
    int r0 = (blockIdx.x * 4 + wave) * 16;

    // ---- row metadata (forced scalar) ----
    int s[16], c[16], maxc = 0;
#pragma unroll
    for (int r = 0; r < 16; ++r) {
        int row = r0 + r;
        int sv = 0, cv = 0;
        if (row < nrows) { sv = rowptr[row]; cv = deg[row]; }
        s[r] = __builtin_amdgcn_readfirstlane(sv);
        c[r] = __builtin_amdgcn_readfirstlane(cv);
        maxc = max(maxc, c[r]);
    }

    // ---- lane-parallel neighbor-index prefetch: lane i holds csr[s[r]+min(i,c[r]-1)] ----
    int nbr[16];
#pragma unroll
    for (int r = 0; r < 16; ++r) {
        int idx = s[r] + min(lane, max(c[r] - 1, 0));
        nbr[r] = csr[idx];
    }

    float z[16];
#pragma unroll
    for (int r = 0; r < 16; ++r)
        z[r] = (r0 + r < nrows) ? ldbf(&h[(size_t)(r0 + r) * HH + lane]) : 0.0f;

    // ---- gather: index via v_readlane (no csr loads in the loop), 32 h-loads in flight ----
    int jmax = min(maxc, 64);
    for (int j = 0; j < jmax; j += 2) {
        float v0[16], v1[16];
#pragma unroll
        for (int r = 0; r < 16; ++r) {
            int cl = max(c[r] - 1, 0);
            int j0 = min(min(j, cl), 63);
            int j1 = min(min(j + 1, cl), 63);
            int sn0 = __builtin_amdgcn_readlane(nbr[r], j0);
            int sn1 = __builtin_amdgcn_readlane(nbr[r], j1);
            sn0 = min(max(sn0, 0), nrows - 1);
            sn1 = min(max(sn1, 0), nrows - 1);
            v0[r] = ldbf(&h[(size_t)sn0 * HH + lane]);
            v1[r] = ldbf(&h[(size_t)sn1 * HH + lane]);
        }
#pragma unroll
        for (int r = 0; r < 16; ++r) {
            z[r] += (j < c[r]) ? v0[r] : 0.0f;
            z[r] += (j + 1 < c[r]) ? v1[r] : 0.0f;
        }
    }
    if (maxc > 64) {   // astronomically rare for Poisson(10); correctness fallback
        for (int r = 0; r < 16; ++r) {
            for (int j = 64; j < c[r]; ++j) {
                int sn = csr[s[r] + j];
                sn = min(max(sn, 0), nrows - 1);
                z[r] += ldbf(&h[(size_t)sn * HH + lane]);
            }
        }
    }

#pragma unroll
    for (int r = 0; r < 16; ++r)
        *(short*)(ldsb + r * 128 + ((lane * 2) ^ ((r & 7) << 4))) = (short)f2bf(z[r]);
    __syncthreads();

    short8 a0, a1;
    f32x4 acc[4];
    // ---- GEMM1 + BN + ReLU ----
    {
        int rr = lane & 15;
        a0 = *(const short8*)(ldsb + rr * 128 + (((lane >> 4) * 16) ^ ((rr & 7) << 4)));
        a1 = *(const short8*)(ldsb + rr * 128 + ((64 + (lane >> 4) * 16) ^ ((rr & 7) << 4)));
    }
#pragma unroll
    for (int tile = 0; tile < 4; ++tile) {
        acc[tile] = (f32x4){0.f, 0.f, 0.f, 0.f};
        acc[tile] = __builtin_amdgcn_mfma_f32_16x16x32_bf16(a0, wfG1[(tile * 2 + 0) * 64 + lane], acc[tile], 0, 0, 0);
        acc[tile] = __builtin_amdgcn_mfma_f32_16x16x32_bf16(a1, wfG1[(tile * 2 + 1) * 64 + lane], acc[tile], 0, 0, 0);
    }
    __syncthreads();
#pragma unroll
    for (int tile = 0; tile < 4; ++tile) {
        int col = tile * 16 + (lane & 15);
        float sc = g1[col] * BN_RSQRT;
        float sh = fmaf(b1[col], sc, bt1[col]);
#pragma unroll
        for (int q = 0; q < 4; ++q) {
            int row = (lane >> 4) * 4 + q;
            float v = fmaxf(fmaf(acc[tile][q], sc, sh), 0.0f);
            *(short*)(ldsb + row * 128 + ((col * 2) ^ ((row & 7) << 4))) = (short)f2bf(v);
        }
    }
    __syncthreads();

    // ---- GEMM2 + BN + ReLU ----
    {
        int rr = lane & 15;
        a0 = *(const short8*)(ldsb + rr * 128 + (((lane >> 4) * 16) ^ ((rr & 7) << 4)));
        a1 = *(const short8*)(ldsb + rr * 128 + ((64 + (lane >> 4) * 16) ^ ((rr & 7) << 4)));
    }
#pragma unroll
    for (int tile = 0; tile < 4; ++tile) {
        acc[tile] = (f32x4){0.f, 0.f, 0.f, 0.f};
        acc[tile] = __builtin_amdgcn_mfma_f32_16x16x32_bf16(a0, wfG2[(tile * 2 + 0) * 64 + lane], acc[tile], 0, 0, 0);
        acc[tile] = __builtin_amdgcn_mfma_f32_16x16x32_bf16(a1, wfG2[(tile * 2 + 1) * 64 + lane], acc[tile], 0, 0, 0);
    }
    __syncthreads();
#pragma unroll
    for (int tile = 0; tile < 4; ++tile) {
        int col = tile * 16 + (lane & 15);
        float sc = g2[col] * BN_RSQRT;
        float sh = fmaf(b2[col], sc, bt2[col]);
#pragma unroll
        for (int q = 0; q < 4; ++q) {
            int row = (lane >> 4) * 4 + q;
            float v = fmaxf(fmaf(acc[tile][q], sc, sh), 0.0f);
            *(short*)(ldsb + row * 128 + ((col * 2) ^ ((row & 7) << 4))) = (short)f2bf(v);
        }
    }
    __syncthreads();

    if (FINAL == 0) {
#pragma unroll
        for (int half = 0; half < 2; ++half) {
            int row = (lane >> 3) + half * 8;
            short8 vv = *(const short8*)(ldsb + row * 128 + ((((lane & 7) * 16)) ^ ((row & 7) << 4)));
            int grow = r0 + row;
            if (grow < nrows)
                *(short8*)((char*)out + (size_t)grow * 128 + (lane & 7) * 16) = vv;
        }
    } else {
        // ---- GEMM3: relu(h4 @ Wl1 + bl1) ----
        {
            int rr = lane & 15;
            a0 = *(const short8*)(ldsb + rr * 128 + (((lane >> 4) * 16) ^ ((rr & 7) << 4)));
            a1 = *(const short8*)(ldsb + rr * 128 + ((64 + (lane >> 4) * 16) ^ ((rr & 7) << 4)));
        }
#pragma unroll
        for (int tile = 0; tile < 4; ++tile) {
            acc[tile] = (f32x4){0.f, 0.f, 0.f, 0.f};
            acc[tile] = __builtin_amdgcn_mfma_f32_16x16x32_bf16(a0, wfL1[(tile * 2 + 0) * 64 + lane], acc[tile], 0, 0, 0);
            acc[tile] = __builtin_amdgcn_mfma_f32_16x16x32_bf16(a1, wfL1[(tile * 2 + 1) * 64 + lane], acc[tile], 0, 0, 0);
        }
        __syncthreads();
#pragma unroll
        for (int tile = 0; tile < 4; ++tile) {
            int col = tile * 16 + (lane & 15);
            float bia = bl1[col];
#pragma unroll
            for (int q = 0; q < 4; ++q) {
                int row = (lane >> 4) * 4 + q;
                float v = fmaxf(acc[tile][q] + bia, 0.0f);
                *(short*)(ldsb + row * 128 + ((col * 2) ^ ((row & 7) << 4))) = (short)f2bf(v);
            }
        }
        __syncthreads();
        // ---- in-kernel mean-pool partials (run-length flush, batch sorted) ----
        float pacc = 0.0f;
        int curg = -1, rc = 0;
        for (int r = 0; r < 16; ++r) {
            int row = r0 + r;
            if (row >= nrows) break;
            float v = us2f(*(const unsigned short*)(ldsb + r * 128 + ((lane * 2) ^ ((r & 7) << 4))));
            int g = batch[row];
            if (g != curg) {
                if (curg >= 0) {
                    atomicAdd(&pooled[curg * HH + lane], pacc);
                    if (lane == 0) atomicAdd(&cnt[curg], (float)rc);
                }
                curg = g; pacc = v; rc = 1;
            } else { pacc += v; rc += 1; }
        }
        if (curg >= 0) {
            atomicAdd(&pooled[curg * HH + lane], pacc);
            if (lane == 0) atomicAdd(&cnt[curg], (float)rc);
        }
    }
}

__global__ __launch_bounds__(64) void head_kernel(
    const float* __restrict__ pooled, const float* __restrict__ cnt,
    const float* __restrict__ Wl2, const float* __restrict__ bl2,
    float* __restrict__ out, int ngraphs)
{
    int gidx = blockIdx.x * 64 + threadIdx.x;
    if (gidx >= ngraphs) return;
    float logits[CC];
#pragma unroll
    for (int c = 0; c < CC; ++c) logits[c] = bl2[c];
    float inv_n = 1.0f / fmaxf(cnt[gidx], 1.0f);
    for (int k = 0; k < HH; ++k) {
        float p = pooled[gidx * HH + k] * inv_n;
#pragma unroll
        for (int c = 0; c < CC; ++c) logits[c] = fmaf(p, Wl2[k * CC + c], logits[c]);
    }
    float m = logits[0];
#pragma unroll
    for (int c = 1; c < CC; ++c) m = fmaxf(m, logits[c]);
    float ssum = 0.0f;
#pragma unroll
    for (int c = 0; c < CC; ++c) { logits[c] = __expf(logits[c] - m); ssum += logits[c]; }
    float inv = 1.0f / ssum;
#pragma unroll
    for (int c = 0; c < CC; ++c) out[gidx * CC + c] = logits[c] * inv;
}

extern "C" void kernel_launch(void* const* d_in, const int* in_sizes, int n_in,
                              void* d_out, int out_size, void* d_ws, size_t ws_size,
                              hipStream_t stream) {
    const float* x      = (const float*)d_in[0];
    const int*   ei     = (const int*)  d_in[1];
    const int*   batch  = (const int*)  d_in[3];
    const float* W0     = (const float*)d_in[4];
    const float* b0     = (const float*)d_in[5];
    const float* convW1 = (const float*)d_in[6];
    const float* convb1 = (const float*)d_in[7];
    const float* convg1 = (const float*)d_in[8];
    const float* convbt1= (const float*)d_in[9];
    const float* convW2 = (const float*)d_in[10];
    const float* convb2 = (const float*)d_in[11];
    const float* convg2 = (const float*)d_in[12];
    const float* convbt2= (const float*)d_in[13];
    const float* Wl1    = (const float*)d_in[14];
    const float* bl1    = (const float*)d_in[15];
    const float* Wl2    = (const float*)d_in[16];
    const float* bl2    = (const float*)d_in[17];

    const int N = in_sizes[0] / FF;
    const int E = in_sizes[1] / 2;
    const int G = out_size / CC;

    const int* src = ei;
    const int* dst = ei + E;

    size_t off = 0;
    auto take = [&](size_t bytes) { size_t p = off; off = (off + bytes + 255) & ~255ULL; return p; };
    int NB = (N + 255) / 256;
    int EB = (E + 255) / 256;
    size_t o_rowptr = take((size_t)N * 4);
    size_t o_deg    = take((size_t)N * 4);
    size_t o_csr    = take((size_t)(E > NB ? E : NB) * 4 + 512);
    size_t o_pooled = take((size_t)G * HH * 4);
    size_t o_cnt    = take((size_t)G * 4);
    size_t o_wfrag  = take((size_t)5632 * 8 * 2);
    size_t o_hA     = take((size_t)N * HH * 2);
    size_t o_hB     = take((size_t)N * HH * 2);

    char* base = (char*)d_ws;
    int*    rowptr = (int*)(base + o_rowptr);
    int*    deg    = (int*)(base + o_deg);
    int*    csr    = (int*)(base + o_csr);
    float*  pooled = (float*)(base + o_pooled);
    float*  cnt    = (float*)(base + o_cnt);
    short*  wfrag  = (short*)(base + o_wfrag);
    short8* wf8    = (short8*)wfrag;
    bf16*   hA     = (bf16*)(base + o_hA);
    bf16*   hB     = (bf16*)(base + o_hB);

    int tile_blocks = (N + 63) / 64;     // 4 waves x 16 rows

    // weight fragment packing
    pack_weights_kernel<<<22, 256, 0, stream>>>(W0, convW1, convW2, Wl1, wfrag);

    // CSR build
    hipMemsetAsync(deg, 0, (size_t)N * sizeof(int), stream);
    hist_kernel<<<EB, 256, 0, stream>>>(dst, deg, E);
    scan_block_kernel<<<NB, 256, 0, stream>>>(deg, rowptr, csr /*partials*/, N);
    scan_partials_kernel<<<1, 256, 0, stream>>>(csr, NB);
    add_offsets_kernel<<<NB, 256, 0, stream>>>(rowptr, csr, N);
    hipMemsetAsync(deg, 0, (size_t)N * sizeof(int), stream);
    {
        int stride = ((E + 3) / 4 + 255) & ~255;
        place_kernel<<<stride / 256, 256, 0, stream>>>(src, dst, rowptr, deg, csr, E, stride);
    }

    // lin0
    lin0_kernel<<<tile_blocks, 256, 0, stream>>>(x, wf8, b0, hA, N);

    // pooled/cnt init (before final fused layer)
    hipMemsetAsync(pooled, 0, (size_t)G * HH * sizeof(float), stream);
    hipMemsetAsync(cnt, 0, (size_t)G * sizeof(float), stream);

    // layers (ping-pong); last layer fuses final linear + pooling
    const bf16* hin = hA; bf16* hout = hB;
    const short8* wfL1 = wf8 + 5120;
    for (int l = 0; l < LL; ++l) {
        const short8* wfG1 = wf8 + 1024 + (size_t)(l * 2 + 0) * 512;
        const short8* wfG2 = wf8 + 1024 + (size_t)(l * 2 + 1) * 512;
        if (l < LL - 1) {
            layer_kernel<0><<<tile_blocks, 256, 0, stream>>>(
                hin, rowptr, deg, csr, wfG1, wfG2,
                convb1 + l * HH, convg1 + l * HH, convbt1 + l * HH,
                convb2 + l * HH, convg2 + l * HH, convbt2 + l * HH,
                hout, N, nullptr, nullptr, nullptr, nullptr, nullptr);
        } else {
            layer_kernel<1><<<tile_blocks, 256, 0, stream>>>(
                hin, rowptr, deg, csr, wfG1, wfG2,
                convb1 + l * HH, convg1 + l * HH, convbt1 + l * HH,
                convb2 + l * HH, convg2 + l * HH, convbt2 + l * HH,
                nullptr, N, wfL1, bl1, batch, pooled, cnt);
        }
        bf16* tswap = (bf16*)hin; hin = hout; hout = tswap;
    }

    head_kernel<<<(G + 63) / 64, 64, 0, stream>>>(pooled, cnt, Wl2, bl2, (float*)d_out, G);
}

// Round 7
// 354.961 us; speedup vs baseline: 5.2723x; 1.0465x over previous
//
#include <hip/hip_runtime.h>
#include <hip/hip_bf16.h>

#define HH 64
#define FF 128
#define CC 10
#define LL 4
#define BN_RSQRT 0.9999950000374997f   // 1/sqrt(1+1e-5)

typedef __hip_bfloat16 bf16;
using short8 = __attribute__((ext_vector_type(8))) short;
using f32x4  = __attribute__((ext_vector_type(4))) float;

__device__ __forceinline__ float ldbf(const bf16* p) {
    return __uint_as_float(((unsigned)*(const unsigned short*)p) << 16);
}
__device__ __forceinline__ float us2f(unsigned short u) {
    return __uint_as_float(((unsigned)u) << 16);
}
// RNE f32->bf16 bits (finite inputs)
__device__ __forceinline__ unsigned short f2bf(float v) {
    unsigned u = __float_as_uint(v);
    return (unsigned short)((u + 0x7FFFu + ((u >> 16) & 1u)) >> 16);
}

// ---------- weight fragment packing ----------
// B-frag layout for mfma_f32_16x16x32_bf16: lane l holds B[k][n] with
// n = tile*16 + (l&15), k = kc*32 + (l>>4)*8 + e, e=0..7.
__global__ __launch_bounds__(256) void pack_weights_kernel(
    const float* __restrict__ W0, const float* __restrict__ convW1,
    const float* __restrict__ convW2, const float* __restrict__ Wl1,
    short* __restrict__ wf)
{
    int t = blockIdx.x * 256 + threadIdx.x;
    if (t >= 5632) return;
    const float* W;
    int l, tile, kc, out_idx;
    if (t < 1024) {
        int local = t; int fi = local >> 6; l = local & 63;
        tile = fi >> 2; kc = fi & 3;
        W = W0; out_idx = local;
    } else if (t < 5120) {
        int t2 = t - 1024;
        int m = t2 >> 9;
        int local = t2 & 511;
        int fi = local >> 6; l = local & 63;
        tile = fi >> 1; kc = fi & 1;
        int layer = m >> 1, g = m & 1;
        W = (g ? convW2 : convW1) + (size_t)layer * HH * HH;
        out_idx = 1024 + m * 512 + local;
    } else {
        int local = t - 5120;
        int fi = local >> 6; l = local & 63;
        tile = fi >> 1; kc = fi & 1;
        W = Wl1; out_idx = 5120 + local;
    }
    int k0 = kc * 32 + (l >> 4) * 8;
    int n = tile * 16 + (l & 15);
#pragma unroll
    for (int e = 0; e < 8; ++e)
        wf[out_idx * 8 + e] = (short)f2bf(W[(k0 + e) * HH + n]);
}

// ---------- lin0 (MFMA): h = relu(x @ W0 + b0) ----------
__global__ __launch_bounds__(256) void lin0_kernel(
    const float* __restrict__ x, const short8* __restrict__ wf0,
    const float* __restrict__ b0, bf16* __restrict__ h, int nrows)
{
    __shared__ __align__(16) short lds_all[4][2048];   // per wave [16][128] bf16
    int wave = __builtin_amdgcn_readfirstlane(threadIdx.x >> 6);
    int lane = threadIdx.x & 63;
    char* ldsb = (char*)&lds_all[wave][0];
    int r0 = (blockIdx.x * 4 + wave) * 16;

#pragma unroll
    for (int r = 0; r < 16; ++r) {
        int row = r0 + r;
        float2 xv = make_float2(0.f, 0.f);
        if (row < nrows) xv = *(const float2*)(x + (size_t)row * FF + lane * 2);
        unsigned pk = (unsigned)f2bf(xv.x) | ((unsigned)f2bf(xv.y) << 16);
        *(int*)(ldsb + r * 256 + ((lane * 4) ^ ((r & 7) << 4))) = pk;
    }
    __syncthreads();

    short8 a[4];
#pragma unroll
    for (int kc = 0; kc < 4; ++kc) {
        int rr = lane & 15;
        a[kc] = *(const short8*)(ldsb + rr * 256 + (((kc * 64 + (lane >> 4) * 16)) ^ ((rr & 7) << 4)));
    }
    f32x4 acc[4];
#pragma unroll
    for (int tile = 0; tile < 4; ++tile) {
        acc[tile] = (f32x4){0.f, 0.f, 0.f, 0.f};
#pragma unroll
        for (int kc = 0; kc < 4; ++kc) {
            short8 b = wf0[(tile * 4 + kc) * 64 + lane];
            acc[tile] = __builtin_amdgcn_mfma_f32_16x16x32_bf16(a[kc], b, acc[tile], 0, 0, 0);
        }
    }
    __syncthreads();
#pragma unroll
    for (int tile = 0; tile < 4; ++tile) {
        int col = tile * 16 + (lane & 15);
        float bia = b0[col];
#pragma unroll
        for (int q = 0; q < 4; ++q) {
            int row = (lane >> 4) * 4 + q;
            float v = fmaxf(acc[tile][q] + bia, 0.0f);
            *(short*)(ldsb + row * 256 + ((col * 2) ^ ((row & 7) << 4))) = (short)f2bf(v);
        }
    }
    __syncthreads();
#pragma unroll
    for (int half = 0; half < 2; ++half) {
        int row = (lane >> 3) + half * 8;
        short8 vv = *(const short8*)(ldsb + row * 256 + ((((lane & 7) * 16)) ^ ((row & 7) << 4)));
        int grow = r0 + row;
        if (grow < nrows)
            *(short8*)((char*)h + (size_t)grow * 128 + (lane & 7) * 16) = vv;
    }
}

// ---------- CSR build ----------
__global__ __launch_bounds__(256) void hist_kernel(
    const int* __restrict__ dst, int* __restrict__ deg, int nedges)
{
    int e = blockIdx.x * 256 + threadIdx.x;
    if (e < nedges) atomicAdd(&deg[dst[e]], 1);
}

__global__ __launch_bounds__(256) void scan_block_kernel(
    const int* __restrict__ deg, int* __restrict__ rowptr,
    int* __restrict__ partials, int n)
{
    __shared__ int sm[256];
    int tid = threadIdx.x;
    int i = blockIdx.x * 256 + tid;
    int v = (i < n) ? deg[i] : 0;
    sm[tid] = v;
    __syncthreads();
    for (int ofs = 1; ofs < 256; ofs <<= 1) {
        int t = (tid >= ofs) ? sm[tid - ofs] : 0;
        __syncthreads();
        sm[tid] += t;
        __syncthreads();
    }
    if (i < n) rowptr[i] = sm[tid] - v;
    if (tid == 255) partials[blockIdx.x] = sm[255];
}

__global__ __launch_bounds__(256) void scan_partials_kernel(int* partials, int nb)
{
    __shared__ int sm[256];
    __shared__ int carry;
    int tid = threadIdx.x;
    if (tid == 0) carry = 0;
    __syncthreads();
    for (int base = 0; base < nb; base += 256) {
        int i = base + tid;
        int v = (i < nb) ? partials[i] : 0;
        sm[tid] = v;
        __syncthreads();
        for (int ofs = 1; ofs < 256; ofs <<= 1) {
            int t = (tid >= ofs) ? sm[tid - ofs] : 0;
            __syncthreads();
            sm[tid] += t;
            __syncthreads();
        }
        int cbase = carry;
        int tot = sm[255];
        if (i < nb) partials[i] = sm[tid] - v + cbase;
        __syncthreads();
        if (tid == 0) carry = cbase + tot;
        __syncthreads();
    }
}

__global__ __launch_bounds__(256) void add_offsets_kernel(
    int* __restrict__ rowptr, const int* __restrict__ partials, int n)
{
    int i = blockIdx.x * 256 + threadIdx.x;
    if (i < n) rowptr[i] += partials[blockIdx.x];
}

// 4 strided edges per thread -> 4 independent atomic->store chains in flight
__global__ __launch_bounds__(256) void place_kernel(
    const int* __restrict__ src, const int* __restrict__ dst,
    const int* __restrict__ rowptr, int* __restrict__ deg,
    int* __restrict__ csr, int nedges, int stride)
{
    int t = blockIdx.x * 256 + threadIdx.x;
    int e[4], d[4], slot[4];
    bool ok[4];
#pragma unroll
    for (int i = 0; i < 4; ++i) {
        e[i] = t + i * stride;
        ok[i] = e[i] < nedges;
        d[i] = ok[i] ? dst[e[i]] : 0;
    }
#pragma unroll
    for (int i = 0; i < 4; ++i)
        slot[i] = ok[i] ? atomicAdd(&deg[d[i]], 1) : 0;
#pragma unroll
    for (int i = 0; i < 4; ++i)
        if (ok[i]) csr[rowptr[d[i]] + slot[i]] = src[e[i]];
}

// ---------- fused MFMA layer (FINAL adds 3rd GEMM + in-kernel pooling) ----------
// Gather uses 4-row fat loads: lane l serves row 4g+(l>>4), features (l&15)*4..+3,
// one global_load_dwordx2 per (j, group) fetches 4 rows x 8B x 16 lanes = 512B.
template <int FINAL>
__global__ __launch_bounds__(256) void layer_kernel(
    const bf16* __restrict__ h, const int* __restrict__ rowptr,
    const int* __restrict__ deg, const int* __restrict__ csr,
    const short8* __restrict__ wfG1, const short8* __restrict__ wfG2,
    const float* __restrict__ b1, const float* __restrict__ g1, const float* __restrict__ bt1,
    const float* __restrict__ b2, const float* __restrict__ g2, const float* __restrict__ bt2,
    bf16* __restrict__ out, int nrows,
    const short8* __restrict__ wfL1, const float* __restrict__ bl1,
    const int* __restrict__ batch, float* __restrict__ pooled, float* __restrict__ cnt)
{
    __shared__ __align__(16) short lds_all[4][1024];   // per wave [16][64] bf16
    int wave = __builtin_amdgcn_readfirstlane(threadIdx.x >> 6);
    int lane = threadIdx.x & 63;
    char* ldsb = (char*)&lds_all[wave][0];
    int r0 = (blockIdx.x * 4 + wave) * 16;

    // ---- row metadata (forced scalar) ----
    int s[16], c[16], maxc = 0;
#pragma unroll
    for (int r = 0; r < 16; ++r) {
        int row = r0 + r;
        int sv = 0, cv = 0;
        if (row < nrows) { sv = rowptr[row]; cv = deg[row]; }
        s[r] = __builtin_amdgcn_readfirstlane(sv);
        c[r] = __builtin_amdgcn_readfirstlane(cv);
        maxc = max(maxc, c[r]);
    }

    // ---- lane-parallel neighbor-index prefetch: lane i holds csr[s[r]+min(i,c[r]-1)] ----
    int nbr[16];
#pragma unroll
    for (int r = 0; r < 16; ++r)
        nbr[r] = csr[s[r] + min(lane, max(c[r] - 1, 0))];

    int selrow = lane >> 4;          // which row of the 4-row group this lane serves
    int fq8 = (lane & 15) * 8;       // byte offset of this lane's feature quad

    // per-lane degree of my row, per group
    int myc[4];
#pragma unroll
    for (int g = 0; g < 4; ++g) {
        int m = c[g * 4 + 0];
        m = (selrow == 1) ? c[g * 4 + 1] : m;
        m = (selrow == 2) ? c[g * 4 + 2] : m;
        m = (selrow == 3) ? c[g * 4 + 3] : m;
        myc[g] = m;
    }

    // ---- z init: self rows, 4-row fat loads ----
    float zg[4][4];
#pragma unroll
    for (int g = 0; g < 4; ++g) {
        int row = r0 + g * 4 + selrow;
        int rc = min(row, nrows - 1);
        uint2 v = *(const uint2*)((const char*)h + (size_t)rc * 128 + fq8);
        bool ok = row < nrows;
        zg[g][0] = ok ? us2f((unsigned short)(v.x & 0xffffu)) : 0.f;
        zg[g][1] = ok ? us2f((unsigned short)(v.x >> 16)) : 0.f;
        zg[g][2] = ok ? us2f((unsigned short)(v.y & 0xffffu)) : 0.f;
        zg[g][3] = ok ? us2f((unsigned short)(v.y >> 16)) : 0.f;
    }

    // ---- gather: j unrolled x4, 16 fat loads (8KB) in flight per wave ----
    int jmax = min(maxc, 64);
    for (int j0 = 0; j0 < jmax; j0 += 4) {
        uint2 vv[4][4];   // [jj][g] — all indices static after unroll
#pragma unroll
        for (int jj = 0; jj < 4; ++jj) {
            int j = j0 + jj;
#pragma unroll
            for (int g = 0; g < 4; ++g) {
                int q0 = g * 4;
                int i0 = __builtin_amdgcn_readlane(nbr[q0 + 0], min(min(j, max(c[q0 + 0] - 1, 0)), 63));
                int i1 = __builtin_amdgcn_readlane(nbr[q0 + 1], min(min(j, max(c[q0 + 1] - 1, 0)), 63));
                int i2 = __builtin_amdgcn_readlane(nbr[q0 + 2], min(min(j, max(c[q0 + 2] - 1, 0)), 63));
                int i3 = __builtin_amdgcn_readlane(nbr[q0 + 3], min(min(j, max(c[q0 + 3] - 1, 0)), 63));
                int sn = i0;
                sn = (selrow == 1) ? i1 : sn;
                sn = (selrow == 2) ? i2 : sn;
                sn = (selrow == 3) ? i3 : sn;
                sn = min(max(sn, 0), nrows - 1);
                vv[jj][g] = *(const uint2*)((const char*)h + (size_t)sn * 128 + fq8);
            }
        }
#pragma unroll
        for (int jj = 0; jj < 4; ++jj) {
            int j = j0 + jj;
#pragma unroll
            for (int g = 0; g < 4; ++g) {
                bool ok = j < myc[g];
                uint2 v = vv[jj][g];
                zg[g][0] += ok ? us2f((unsigned short)(v.x & 0xffffu)) : 0.f;
                zg[g][1] += ok ? us2f((unsigned short)(v.x >> 16)) : 0.f;
                zg[g][2] += ok ? us2f((unsigned short)(v.y & 0xffffu)) : 0.f;
                zg[g][3] += ok ? us2f((unsigned short)(v.y >> 16)) : 0.f;
            }
        }
    }
    if (maxc > 64) {   // astronomically rare for Poisson(10); correctness fallback
#pragma unroll
        for (int g = 0; g < 4; ++g) {
#pragma unroll
            for (int q = 0; q < 4; ++q) {
                int r = g * 4 + q;
                for (int j = 64; j < c[r]; ++j) {
                    int sn = csr[s[r] + j];
                    sn = min(max(sn, 0), nrows - 1);
                    uint2 v = *(const uint2*)((const char*)h + (size_t)sn * 128 + fq8);
                    bool mine = (selrow == q);
                    zg[g][0] += mine ? us2f((unsigned short)(v.x & 0xffffu)) : 0.f;
                    zg[g][1] += mine ? us2f((unsigned short)(v.x >> 16)) : 0.f;
                    zg[g][2] += mine ? us2f((unsigned short)(v.y & 0xffffu)) : 0.f;
                    zg[g][3] += mine ? us2f((unsigned short)(v.y >> 16)) : 0.f;
                }
            }
        }
    }

    // ---- z -> LDS bf16 [16][64], XOR-swizzled (8B stores, 16B-XOR safe) ----
#pragma unroll
    for (int g = 0; g < 4; ++g) {
        int row = g * 4 + selrow;
        unsigned d0 = (unsigned)f2bf(zg[g][0]) | ((unsigned)f2bf(zg[g][1]) << 16);
        unsigned d1 = (unsigned)f2bf(zg[g][2]) | ((unsigned)f2bf(zg[g][3]) << 16);
        int off = (row * 128 + fq8) ^ ((row & 7) << 4);
        *(uint2*)(ldsb + off) = make_uint2(d0, d1);
    }
    __syncthreads();

    short8 a0, a1;
    f32x4 acc[4];
    // ---- GEMM1 + BN + ReLU ----
    {
        int rr = lane & 15;
        a0 = *(const short8*)(ldsb + rr * 128 + (((lane >> 4) * 16) ^ ((rr & 7) << 4)));
        a1 = *(const short8*)(ldsb + rr * 128 + ((64 + (lane >> 4) * 16) ^ ((rr & 7) << 4)));
    }
#pragma unroll
    for (int tile = 0; tile < 4; ++tile) {
        acc[tile] = (f32x4){0.f, 0.f, 0.f, 0.f};
        acc[tile] = __builtin_amdgcn_mfma_f32_16x16x32_bf16(a0, wfG1[(tile * 2 + 0) * 64 + lane], acc[tile], 0, 0, 0);
        acc[tile] = __builtin_amdgcn_mfma_f32_16x16x32_bf16(a1, wfG1[(tile * 2 + 1) * 64 + lane], acc[tile], 0, 0, 0);
    }
    __syncthreads();
#pragma unroll
    for (int tile = 0; tile < 4; ++tile) {
        int col = tile * 16 + (lane & 15);
        float sc = g1[col] * BN_RSQRT;
        float sh = fmaf(b1[col], sc, bt1[col]);
#pragma unroll
        for (int q = 0; q < 4; ++q) {
            int row = (lane >> 4) * 4 + q;
            float v = fmaxf(fmaf(acc[tile][q], sc, sh), 0.0f);
            *(short*)(ldsb + row * 128 + ((col * 2) ^ ((row & 7) << 4))) = (short)f2bf(v);
        }
    }
    __syncthreads();

    // ---- GEMM2 + BN + ReLU ----
    {
        int rr = lane & 15;
        a0 = *(const short8*)(ldsb + rr * 128 + (((lane >> 4) * 16) ^ ((rr & 7) << 4)));
        a1 = *(const short8*)(ldsb + rr * 128 + ((64 + (lane >> 4) * 16) ^ ((rr & 7) << 4)));
    }
#pragma unroll
    for (int tile = 0; tile < 4; ++tile) {
        acc[tile] = (f32x4){0.f, 0.f, 0.f, 0.f};
        acc[tile] = __builtin_amdgcn_mfma_f32_16x16x32_bf16(a0, wfG2[(tile * 2 + 0) * 64 + lane], acc[tile], 0, 0, 0);
        acc[tile] = __builtin_amdgcn_mfma_f32_16x16x32_bf16(a1, wfG2[(tile * 2 + 1) * 64 + lane], acc[tile], 0, 0, 0);
    }
    __syncthreads();
#pragma unroll
    for (int tile = 0; tile < 4; ++tile) {
        int col = tile * 16 + (lane & 15);
        float sc = g2[col] * BN_RSQRT;
        float sh = fmaf(b2[col], sc, bt2[col]);
#pragma unroll
        for (int q = 0; q < 4; ++q) {
            int row = (lane >> 4) * 4 + q;
            float v = fmaxf(fmaf(acc[tile][q], sc, sh), 0.0f);
            *(short*)(ldsb + row * 128 + ((col * 2) ^ ((row & 7) << 4))) = (short)f2bf(v);
        }
    }
    __syncthreads();

    if (FINAL == 0) {
#pragma unroll
        for (int half = 0; half < 2; ++half) {
            int row = (lane >> 3) + half * 8;
            short8 vv = *(const short8*)(ldsb + row * 128 + ((((lane & 7) * 16)) ^ ((row & 7) << 4)));
            int grow = r0 + row;
            if (grow < nrows)
                *(short8*)((char*)out + (size_t)grow * 128 + (lane & 7) * 16) = vv;
        }
    } else {
        // ---- GEMM3: relu(h4 @ Wl1 + bl1) ----
        {
            int rr = lane & 15;
            a0 = *(const short8*)(ldsb + rr * 128 + (((lane >> 4) * 16) ^ ((rr & 7) << 4)));
            a1 = *(const short8*)(ldsb + rr * 128 + ((64 + (lane >> 4) * 16) ^ ((rr & 7) << 4)));
        }
#pragma unroll
        for (int tile = 0; tile < 4; ++tile) {
            acc[tile] = (f32x4){0.f, 0.f, 0.f, 0.f};
            acc[tile] = __builtin_amdgcn_mfma_f32_16x16x32_bf16(a0, wfL1[(tile * 2 + 0) * 64 + lane], acc[tile], 0, 0, 0);
            acc[tile] = __builtin_amdgcn_mfma_f32_16x16x32_bf16(a1, wfL1[(tile * 2 + 1) * 64 + lane], acc[tile], 0, 0, 0);
        }
        __syncthreads();
#pragma unroll
        for (int tile = 0; tile < 4; ++tile) {
            int col = tile * 16 + (lane & 15);
            float bia = bl1[col];
#pragma unroll
            for (int q = 0; q < 4; ++q) {
                int row = (lane >> 4) * 4 + q;
                float v = fmaxf(acc[tile][q] + bia, 0.0f);
                *(short*)(ldsb + row * 128 + ((col * 2) ^ ((row & 7) << 4))) = (short)f2bf(v);
            }
        }
        __syncthreads();
        // ---- in-kernel mean-pool partials (run-length flush, batch sorted) ----
        float pacc = 0.0f;
        int curg = -1, rc = 0;
        for (int r = 0; r < 16; ++r) {
            int row = r0 + r;
            if (row >= nrows) break;
            float v = us2f(*(const unsigned short*)(ldsb + r * 128 + ((lane * 2) ^ ((r & 7) << 4))));
            int g = batch[row];
            if (g != curg) {
                if (curg >= 0) {
                    atomicAdd(&pooled[curg * HH + lane], pacc);
                    if (lane == 0) atomicAdd(&cnt[curg], (float)rc);
                }
                curg = g; pacc = v; rc = 1;
            } else { pacc += v; rc += 1; }
        }
        if (curg >= 0) {
            atomicAdd(&pooled[curg * HH + lane], pacc);
            if (lane == 0) atomicAdd(&cnt[curg], (float)rc);
        }
    }
}

__global__ __launch_bounds__(64) void head_kernel(
    const float* __restrict__ pooled, const float* __restrict__ cnt,
    const float* __restrict__ Wl2, const float* __restrict__ bl2,
    float* __restrict__ out, int ngraphs)
{
    int gidx = blockIdx.x * 64 + threadIdx.x;
    if (gidx >= ngraphs) return;
    float logits[CC];
#pragma unroll
    for (int c = 0; c < CC; ++c) logits[c] = bl2[c];
    float inv_n = 1.0f / fmaxf(cnt[gidx], 1.0f);
    for (int k = 0; k < HH; ++k) {
        float p = pooled[gidx * HH + k] * inv_n;
#pragma unroll
        for (int c = 0; c < CC; ++c) logits[c] = fmaf(p, Wl2[k * CC + c], logits[c]);
    }
    float m = logits[0];
#pragma unroll
    for (int c = 1; c < CC; ++c) m = fmaxf(m, logits[c]);
    float ssum = 0.0f;
#pragma unroll
    for (int c = 0; c < CC; ++c) { logits[c] = __expf(logits[c] - m); ssum += logits[c]; }
    float inv = 1.0f / ssum;
#pragma unroll
    for (int c = 0; c < CC; ++c) out[gidx * CC + c] = logits[c] * inv;
}

extern "C" void kernel_launch(void* const* d_in, const int* in_sizes, int n_in,
                              void* d_out, int out_size, void* d_ws, size_t ws_size,
                              hipStream_t stream) {
    const float* x      = (const float*)d_in[0];
    const int*   ei     = (const int*)  d_in[1];
    const int*   batch  = (const int*)  d_in[3];
    const float* W0     = (const float*)d_in[4];
    const float* b0     = (const float*)d_in[5];
    const float* convW1 = (const float*)d_in[6];
    const float* convb1 = (const float*)d_in[7];
    const float* convg1 = (const float*)d_in[8];
    const float* convbt1= (const float*)d_in[9];
    const float* convW2 = (const float*)d_in[10];
    const float* convb2 = (const float*)d_in[11];
    const float* convg2 = (const float*)d_in[12];
    const float* convbt2= (const float*)d_in[13];
    const float* Wl1    = (const float*)d_in[14];
    const float* bl1    = (const float*)d_in[15];
    const float* Wl2    = (const float*)d_in[16];
    const float* bl2    = (const float*)d_in[17];

    const int N = in_sizes[0] / FF;
    const int E = in_sizes[1] / 2;
    const int G = out_size / CC;

    const int* src = ei;
    const int* dst = ei + E;

    size_t off = 0;
    auto take = [&](size_t bytes) { size_t p = off; off = (off + bytes + 255) & ~255ULL; return p; };
    int NB = (N + 255) / 256;
    int EB = (E + 255) / 256;
    size_t o_rowptr = take((size_t)N * 4);
    size_t o_deg    = take((size_t)N * 4);
    size_t o_csr    = take((size_t)(E > NB ? E : NB) * 4 + 512);
    size_t o_pooled = take((size_t)G * HH * 4);
    size_t o_cnt    = take((size_t)G * 4);
    size_t o_wfrag  = take((size_t)5632 * 8 * 2);
    size_t o_hA     = take((size_t)N * HH * 2);
    size_t o_hB     = take((size_t)N * HH * 2);

    char* base = (char*)d_ws;
    int*    rowptr = (int*)(base + o_rowptr);
    int*    deg    = (int*)(base + o_deg);
    int*    csr    = (int*)(base + o_csr);
    float*  pooled = (float*)(base + o_pooled);
    float*  cnt    = (float*)(base + o_cnt);
    short*  wfrag  = (short*)(base + o_wfrag);
    short8* wf8    = (short8*)wfrag;
    bf16*   hA     = (bf16*)(base + o_hA);
    bf16*   hB     = (bf16*)(base + o_hB);

    int tile_blocks = (N + 63) / 64;     // 4 waves x 16 rows

    // weight fragment packing
    pack_weights_kernel<<<22, 256, 0, stream>>>(W0, convW1, convW2, Wl1, wfrag);

    // CSR build
    hipMemsetAsync(deg, 0, (size_t)N * sizeof(int), stream);
    hist_kernel<<<EB, 256, 0, stream>>>(dst, deg, E);
    scan_block_kernel<<<NB, 256, 0, stream>>>(deg, rowptr, csr /*partials*/, N);
    scan_partials_kernel<<<1, 256, 0, stream>>>(csr, NB);
    add_offsets_kernel<<<NB, 256, 0, stream>>>(rowptr, csr, N);
    hipMemsetAsync(deg, 0, (size_t)N * sizeof(int), stream);
    {
        int stride = ((E + 3) / 4 + 255) & ~255;
        place_kernel<<<stride / 256, 256, 0, stream>>>(src, dst, rowptr, deg, csr, E, stride);
    }

    // lin0
    lin0_kernel<<<tile_blocks, 256, 0, stream>>>(x, wf8, b0, hA, N);

    // pooled/cnt init (before final fused layer)
    hipMemsetAsync(pooled, 0, (size_t)G * HH * sizeof(float), stream);
    hipMemsetAsync(cnt, 0, (size_t)G * sizeof(float), stream);

    // layers (ping-pong); last layer fuses final linear + pooling
    const bf16* hin = hA; bf16* hout = hB;
    const short8* wfL1 = wf8 + 5120;
    for (int l = 0; l < LL; ++l) {
        const short8* wfG1 = wf8 + 1024 + (size_t)(l * 2 + 0) * 512;
        const short8* wfG2 = wf8 + 1024 + (size_t)(l * 2 + 1) * 512;
        if (l < LL - 1) {
            layer_kernel<0><<<tile_blocks, 256, 0, stream>>>(
                hin, rowptr, deg, csr, wfG1, wfG2,
                convb1 + l * HH, convg1 + l * HH, convbt1 + l * HH,
                convb2 + l * HH, convg2 + l * HH, convbt2 + l * HH,
                hout, N, nullptr, nullptr, nullptr, nullptr, nullptr);
        } else {
            layer_kernel<1><<<tile_blocks, 256, 0, stream>>>(
                hin, rowptr, deg, csr, wfG1, wfG2,
                convb1 + l * HH, convg1 + l * HH, convbt1 + l * HH,
                convb2 + l * HH, convg2 + l * HH, convbt2 + l * HH,
                nullptr, N, wfL1, bl1, batch, pooled, cnt);
        }
        bf16* tswap = (bf16*)hin; hin = hout; hout = tswap;
    }

    head_kernel<<<(G + 63) / 64, 64, 0, stream>>>(pooled, cnt, Wl2, bl2, (float*)d_out, G);
}

// Round 9
// 327.132 us; speedup vs baseline: 5.7209x; 1.0851x over previous
//
#include <hip/hip_runtime.h>
#include <hip/hip_bf16.h>

#define HH 64
#define FF 128
#define CC 10
#define LL 4
#define MAXD 32        // LDS neighbor-table depth (tail loop handles deg>32)
#define BN_RSQRT 0.9999950000374997f   // 1/sqrt(1+1e-5)

typedef __hip_bfloat16 bf16;
using short8 = __attribute__((ext_vector_type(8))) short;
using f32x4  = __attribute__((ext_vector_type(4))) float;
using f32x2  = __attribute__((ext_vector_type(2))) float;

__device__ __forceinline__ float us2f(unsigned short u) {
    return __uint_as_float(((unsigned)u) << 16);
}
// RNE f32->bf16 bits (finite inputs)
__device__ __forceinline__ unsigned short f2bf(float v) {
    unsigned u = __float_as_uint(v);
    return (unsigned short)((u + 0x7FFFu + ((u >> 16) & 1u)) >> 16);
}

// ---------- fp8 pack/unpack (HW cvt on gfx950; software fallback) ----------
// Note: selector bools for the HW builtins MUST be compile-time constants ->
// template parameter, not runtime arg.
#if defined(__has_builtin)
#if __has_builtin(__builtin_amdgcn_cvt_pk_f32_fp8) && __has_builtin(__builtin_amdgcn_cvt_pk_fp8_f32)
#define FP8_HW 1
#endif
#endif

#ifdef FP8_HW
template <bool HIGH>
__device__ __forceinline__ f32x2 fp8_dec2(unsigned w) {
    return __builtin_amdgcn_cvt_pk_f32_fp8((int)w, HIGH);
}
__device__ __forceinline__ unsigned fp8_enc4(float f0, float f1, float f2, float f3) {
    int w = 0;
    w = __builtin_amdgcn_cvt_pk_fp8_f32(f0, f1, w, false);
    w = __builtin_amdgcn_cvt_pk_fp8_f32(f2, f3, w, true);
    return (unsigned)w;
}
#else
__device__ __forceinline__ float fp8_dec1(unsigned b) {
    unsigned s = (b & 0x80u) << 24;
    unsigned em = b & 0x7Fu;
    float mag;
    if (em >= 0x08u) mag = __uint_as_float((((em >> 3) + 120u) << 23) | ((em & 7u) << 20));
    else             mag = (float)em * (1.0f / 512.0f);
    return __uint_as_float(__float_as_uint(mag) | s);
}
template <bool HIGH>
__device__ __forceinline__ f32x2 fp8_dec2(unsigned w) {
    unsigned lo = HIGH ? ((w >> 16) & 0xffu) : (w & 0xffu);
    unsigned hi = HIGH ? ((w >> 24) & 0xffu) : ((w >> 8) & 0xffu);
    f32x2 r; r.x = fp8_dec1(lo); r.y = fp8_dec1(hi); return r;
}
__device__ __forceinline__ unsigned fp8_enc1(float v) {
    unsigned u = __float_as_uint(v);
    unsigned s = (u >> 24) & 0x80u;
    float a = fabsf(v);
    if (a >= 448.0f) return s | 0x7Eu;
    if (a < 0.015625f) {
        int m = (int)rintf(a * 512.0f);
        return s | (unsigned)m;
    }
    int e; float m = frexpf(a, &e);
    int E = e + 6;
    int mant = (int)rintf((m * 2.0f - 1.0f) * 8.0f);
    if (mant == 8) { mant = 0; ++E; }
    if (E > 15) return s | 0x7Eu;
    return s | (unsigned)(E << 3) | (unsigned)mant;
}
__device__ __forceinline__ unsigned fp8_enc4(float f0, float f1, float f2, float f3) {
    return fp8_enc1(f0) | (fp8_enc1(f1) << 8) | (fp8_enc1(f2) << 16) | (fp8_enc1(f3) << 24);
}
#endif

// ---------- weight fragment packing ----------
__global__ __launch_bounds__(256) void pack_weights_kernel(
    const float* __restrict__ W0, const float* __restrict__ convW1,
    const float* __restrict__ convW2, const float* __restrict__ Wl1,
    short* __restrict__ wf)
{
    int t = blockIdx.x * 256 + threadIdx.x;
    if (t >= 5632) return;
    const float* W;
    int l, tile, kc, out_idx;
    if (t < 1024) {
        int local = t; int fi = local >> 6; l = local & 63;
        tile = fi >> 2; kc = fi & 3;
        W = W0; out_idx = local;
    } else if (t < 5120) {
        int t2 = t - 1024;
        int m = t2 >> 9;
        int local = t2 & 511;
        int fi = local >> 6; l = local & 63;
        tile = fi >> 1; kc = fi & 1;
        int layer = m >> 1, g = m & 1;
        W = (g ? convW2 : convW1) + (size_t)layer * HH * HH;
        out_idx = 1024 + m * 512 + local;
    } else {
        int local = t - 5120;
        int fi = local >> 6; l = local & 63;
        tile = fi >> 1; kc = fi & 1;
        W = Wl1; out_idx = 5120 + local;
    }
    int k0 = kc * 32 + (l >> 4) * 8;
    int n = tile * 16 + (l & 15);
#pragma unroll
    for (int e = 0; e < 8; ++e)
        wf[out_idx * 8 + e] = (short)f2bf(W[(k0 + e) * HH + n]);
}

// ---------- lin0 (MFMA): h = relu(x @ W0 + b0), out fp8 ----------
__global__ __launch_bounds__(256) void lin0_kernel(
    const float* __restrict__ x, const short8* __restrict__ wf0,
    const float* __restrict__ b0, unsigned char* __restrict__ h, int nrows)
{
    __shared__ __align__(16) short lds_all[4][2048];   // per wave [16][128] bf16
    int wave = __builtin_amdgcn_readfirstlane(threadIdx.x >> 6);
    int lane = threadIdx.x & 63;
    char* ldsb = (char*)&lds_all[wave][0];
    int r0 = (blockIdx.x * 4 + wave) * 16;

#pragma unroll
    for (int r = 0; r < 16; ++r) {
        int row = r0 + r;
        float2 xv = make_float2(0.f, 0.f);
        if (row < nrows) xv = *(const float2*)(x + (size_t)row * FF + lane * 2);
        unsigned pk = (unsigned)f2bf(xv.x) | ((unsigned)f2bf(xv.y) << 16);
        *(int*)(ldsb + r * 256 + ((lane * 4) ^ ((r & 7) << 4))) = pk;
    }
    __syncthreads();

    short8 a[4];
#pragma unroll
    for (int kc = 0; kc < 4; ++kc) {
        int rr = lane & 15;
        a[kc] = *(const short8*)(ldsb + rr * 256 + (((kc * 64 + (lane >> 4) * 16)) ^ ((rr & 7) << 4)));
    }
    f32x4 acc[4];
#pragma unroll
    for (int tile = 0; tile < 4; ++tile) {
        acc[tile] = (f32x4){0.f, 0.f, 0.f, 0.f};
#pragma unroll
        for (int kc = 0; kc < 4; ++kc) {
            short8 b = wf0[(tile * 4 + kc) * 64 + lane];
            acc[tile] = __builtin_amdgcn_mfma_f32_16x16x32_bf16(a[kc], b, acc[tile], 0, 0, 0);
        }
    }
    __syncthreads();
#pragma unroll
    for (int tile = 0; tile < 4; ++tile) {
        int col = tile * 16 + (lane & 15);
        float bia = b0[col];
#pragma unroll
        for (int q = 0; q < 4; ++q) {
            int row = (lane >> 4) * 4 + q;
            float v = fmaxf(acc[tile][q] + bia, 0.0f);
            *(short*)(ldsb + row * 256 + ((col * 2) ^ ((row & 7) << 4))) = (short)f2bf(v);
        }
    }
    __syncthreads();
#pragma unroll
    for (int half = 0; half < 2; ++half) {
        int row = (lane >> 3) + half * 8;
        short8 vv = *(const short8*)(ldsb + row * 256 + ((((lane & 7) * 16)) ^ ((row & 7) << 4)));
        int grow = r0 + row;
        if (grow < nrows) {
            unsigned w0 = fp8_enc4(us2f((unsigned short)vv[0]), us2f((unsigned short)vv[1]),
                                   us2f((unsigned short)vv[2]), us2f((unsigned short)vv[3]));
            unsigned w1 = fp8_enc4(us2f((unsigned short)vv[4]), us2f((unsigned short)vv[5]),
                                   us2f((unsigned short)vv[6]), us2f((unsigned short)vv[7]));
            *(uint2*)(h + (size_t)grow * 64 + (lane & 7) * 8) = make_uint2(w0, w1);
        }
    }
}

// ---------- CSR build ----------
__global__ __launch_bounds__(256) void hist_kernel(
    const int* __restrict__ dst, int* __restrict__ deg, int nedges)
{
    int e = blockIdx.x * 256 + threadIdx.x;
    if (e < nedges) atomicAdd(&deg[dst[e]], 1);
}

__global__ __launch_bounds__(256) void scan_block_kernel(
    const int* __restrict__ deg, int* __restrict__ rowptr,
    int* __restrict__ partials, int n)
{
    __shared__ int sm[256];
    int tid = threadIdx.x;
    int i = blockIdx.x * 256 + tid;
    int v = (i < n) ? deg[i] : 0;
    sm[tid] = v;
    __syncthreads();
    for (int ofs = 1; ofs < 256; ofs <<= 1) {
        int t = (tid >= ofs) ? sm[tid - ofs] : 0;
        __syncthreads();
        sm[tid] += t;
        __syncthreads();
    }
    if (i < n) rowptr[i] = sm[tid] - v;
    if (tid == 255) partials[blockIdx.x] = sm[255];
}

__global__ __launch_bounds__(256) void scan_partials_kernel(int* partials, int nb)
{
    __shared__ int sm[256];
    __shared__ int carry;
    int tid = threadIdx.x;
    if (tid == 0) carry = 0;
    __syncthreads();
    for (int base = 0; base < nb; base += 256) {
        int i = base + tid;
        int v = (i < nb) ? partials[i] : 0;
        sm[tid] = v;
        __syncthreads();
        for (int ofs = 1; ofs < 256; ofs <<= 1) {
            int t = (tid >= ofs) ? sm[tid - ofs] : 0;
            __syncthreads();
            sm[tid] += t;
            __syncthreads();
        }
        int cbase = carry;
        int tot = sm[255];
        if (i < nb) partials[i] = sm[tid] - v + cbase;
        __syncthreads();
        if (tid == 0) carry = cbase + tot;
        __syncthreads();
    }
}

__global__ __launch_bounds__(256) void add_offsets_kernel(
    int* __restrict__ rowptr, const int* __restrict__ partials, int n)
{
    int i = blockIdx.x * 256 + threadIdx.x;
    if (i < n) rowptr[i] += partials[blockIdx.x];
}

__global__ __launch_bounds__(256) void place_kernel(
    const int* __restrict__ src, const int* __restrict__ dst,
    const int* __restrict__ rowptr, int* __restrict__ deg,
    int* __restrict__ csr, int nedges, int stride)
{
    int t = blockIdx.x * 256 + threadIdx.x;
    int e[4], d[4], slot[4];
    bool ok[4];
#pragma unroll
    for (int i = 0; i < 4; ++i) {
        e[i] = t + i * stride;
        ok[i] = e[i] < nedges;
        d[i] = ok[i] ? dst[e[i]] : 0;
    }
#pragma unroll
    for (int i = 0; i < 4; ++i)
        slot[i] = ok[i] ? atomicAdd(&deg[d[i]], 1) : 0;
#pragma unroll
    for (int i = 0; i < 4; ++i)
        if (ok[i]) csr[rowptr[d[i]] + slot[i]] = src[e[i]];
}

// ---------- degree bucketing (counting sort, 64 bins) ----------
__global__ __launch_bounds__(256) void deg_hist_kernel(
    const int* __restrict__ deg, int* __restrict__ dhist, int n)
{
    __shared__ int lh[64];
    int tid = threadIdx.x;
    if (tid < 64) lh[tid] = 0;
    __syncthreads();
    int i = blockIdx.x * 256 + tid;
    if (i < n) atomicAdd(&lh[min(deg[i], 63)], 1);
    __syncthreads();
    if (tid < 64 && lh[tid]) atomicAdd(&dhist[tid], lh[tid]);
}

__global__ __launch_bounds__(64) void bucket_scan_kernel(
    const int* __restrict__ dhist, int* __restrict__ dcnt)
{
    __shared__ int sm[64];
    int t = threadIdx.x;
    sm[t] = dhist[t];
    __syncthreads();
    int acc = 0;
    for (int k = 0; k < t; ++k) acc += sm[k];
    dcnt[t] = acc;          // dcnt starts as the bucket base cursor
}

__global__ __launch_bounds__(256) void perm_place_kernel(
    const int* __restrict__ deg, int* __restrict__ dcnt,
    int* __restrict__ perm, int n)
{
    __shared__ int lh[64], lbase[64];
    int tid = threadIdx.x;
    if (tid < 64) lh[tid] = 0;
    __syncthreads();
    int i = blockIdx.x * 256 + tid;
    int b = 0;
    if (i < n) { b = min(deg[i], 63); atomicAdd(&lh[b], 1); }
    __syncthreads();
    if (tid < 64) {
        int cntb = lh[tid];
        if (cntb) lbase[tid] = atomicAdd(&dcnt[tid], cntb);
        lh[tid] = 0;
    }
    __syncthreads();
    if (i < n) {
        int r = atomicAdd(&lh[b], 1);
        perm[lbase[b] + r] = i;
    }
}

// ---------- fused MFMA layer, fp8 h, LDS neighbor table, zero-row padding ----------
template <int FINAL>
__global__ __launch_bounds__(256) void layer_kernel(
    const unsigned char* __restrict__ h, const int* __restrict__ rowptr,
    const int* __restrict__ deg, const int* __restrict__ csr,
    const int* __restrict__ perm,
    const short8* __restrict__ wfG1, const short8* __restrict__ wfG2,
    const float* __restrict__ b1, const float* __restrict__ g1, const float* __restrict__ bt1,
    const float* __restrict__ b2, const float* __restrict__ g2, const float* __restrict__ bt2,
    unsigned char* __restrict__ out, int nrows,
    const short8* __restrict__ wfL1, const float* __restrict__ bl1,
    const int* __restrict__ batch, float* __restrict__ pooled, float* __restrict__ cnt)
{
    __shared__ __align__(16) short lds_all[4][1024];     // per wave [16][64] bf16
    __shared__ int idx_tab[4][16][MAXD + 4];             // byte offsets; [MAXD] = self
    int wave = __builtin_amdgcn_readfirstlane(threadIdx.x >> 6);
    int lane = threadIdx.x & 63;
    char* ldsb = (char*)&lds_all[wave][0];
    int r0 = (blockIdx.x * 4 + wave) * 16;

    // ---- row metadata (scalar) + neighbor table fill ----
    int s16[16], c16[16], maxc = 0;
#pragma unroll
    for (int r = 0; r < 16; ++r) {
        int gi = r0 + r;
        int pr = nrows;                       // zero row for OOB
        int sv = 0, cv = 0;
        if (gi < nrows) {
            pr = perm ? perm[gi] : gi;
            sv = rowptr[pr]; cv = deg[pr];
        }
        pr = __builtin_amdgcn_readfirstlane(pr);
        s16[r] = __builtin_amdgcn_readfirstlane(sv);
        c16[r] = __builtin_amdgcn_readfirstlane(cv);
        maxc = max(maxc, c16[r]);
        int idxv = nrows;
        if (lane < c16[r]) idxv = csr[s16[r] + lane];
        idxv = min(max(idxv, 0), nrows) << 6;            // byte offset, clamped
        if (lane < MAXD) idx_tab[wave][r][lane] = idxv;
        if (lane == 0) idx_tab[wave][r][MAXD] = pr << 6; // self
    }

    int selrow = lane >> 4;          // row within 4-row group served by this lane
    int fq4 = (lane & 15) * 4;       // fp8 byte offset of this lane's feature quad
    int fq8 = fq4 * 2;               // bf16 byte offset

    // ---- self init (via table, zero-row padded: no masks) ----
    float zg[4][4];
#pragma unroll
    for (int g = 0; g < 4; ++g) {
        int bo = idx_tab[wave][g * 4 + selrow][MAXD];
        unsigned w = *(const unsigned*)(h + bo + fq4);
        f32x2 lo = fp8_dec2<false>(w), hi = fp8_dec2<true>(w);
        zg[g][0] = lo.x; zg[g][1] = lo.y; zg[g][2] = hi.x; zg[g][3] = hi.y;
    }

    // ---- gather main loop: all dummy slots read the zero row (cached) ----
    int jm = min(maxc, MAXD);
    for (int j0 = 0; j0 < jm; j0 += 4) {
        unsigned w[4][4];
#pragma unroll
        for (int jj = 0; jj < 4; ++jj) {
            int jcl = min(j0 + jj, MAXD - 1);
#pragma unroll
            for (int g = 0; g < 4; ++g) {
                int bo = idx_tab[wave][g * 4 + selrow][jcl];
                w[jj][g] = *(const unsigned*)(h + bo + fq4);
            }
        }
#pragma unroll
        for (int jj = 0; jj < 4; ++jj)
#pragma unroll
            for (int g = 0; g < 4; ++g) {
                f32x2 lo = fp8_dec2<false>(w[jj][g]), hi = fp8_dec2<true>(w[jj][g]);
                zg[g][0] += lo.x; zg[g][1] += lo.y; zg[g][2] += hi.x; zg[g][3] += hi.y;
            }
    }
    if (maxc > MAXD) {    // rare tail, scalar per row
#pragma unroll
        for (int g = 0; g < 4; ++g) {
#pragma unroll
            for (int q = 0; q < 4; ++q) {
                int r = g * 4 + q;
                for (int j = MAXD; j < c16[r]; ++j) {
                    int sn = csr[s16[r] + j];
                    sn = min(max(sn, 0), nrows - 1);
                    unsigned w = *(const unsigned*)(h + ((size_t)sn << 6) + fq4);
                    f32x2 lo = fp8_dec2<false>(w), hi = fp8_dec2<true>(w);
                    bool mine = (selrow == q);
                    zg[g][0] += mine ? lo.x : 0.f;
                    zg[g][1] += mine ? lo.y : 0.f;
                    zg[g][2] += mine ? hi.x : 0.f;
                    zg[g][3] += mine ? hi.y : 0.f;
                }
            }
        }
    }

    // ---- z -> LDS bf16 [16][64], XOR-swizzled ----
#pragma unroll
    for (int g = 0; g < 4; ++g) {
        int row = g * 4 + selrow;
        unsigned d0 = (unsigned)f2bf(zg[g][0]) | ((unsigned)f2bf(zg[g][1]) << 16);
        unsigned d1 = (unsigned)f2bf(zg[g][2]) | ((unsigned)f2bf(zg[g][3]) << 16);
        int off = (row * 128 + fq8) ^ ((row & 7) << 4);
        *(uint2*)(ldsb + off) = make_uint2(d0, d1);
    }
    __syncthreads();

    short8 a0, a1;
    f32x4 acc[4];
    // ---- GEMM1 + BN + ReLU ----
    {
        int rr = lane & 15;
        a0 = *(const short8*)(ldsb + rr * 128 + (((lane >> 4) * 16) ^ ((rr & 7) << 4)));
        a1 = *(const short8*)(ldsb + rr * 128 + ((64 + (lane >> 4) * 16) ^ ((rr & 7) << 4)));
    }
#pragma unroll
    for (int tile = 0; tile < 4; ++tile) {
        acc[tile] = (f32x4){0.f, 0.f, 0.f, 0.f};
        acc[tile] = __builtin_amdgcn_mfma_f32_16x16x32_bf16(a0, wfG1[(tile * 2 + 0) * 64 + lane], acc[tile], 0, 0, 0);
        acc[tile] = __builtin_amdgcn_mfma_f32_16x16x32_bf16(a1, wfG1[(tile * 2 + 1) * 64 + lane], acc[tile], 0, 0, 0);
    }
    __syncthreads();
#pragma unroll
    for (int tile = 0; tile < 4; ++tile) {
        int col = tile * 16 + (lane & 15);
        float sc = g1[col] * BN_RSQRT;
        float sh = fmaf(b1[col], sc, bt1[col]);
#pragma unroll
        for (int q = 0; q < 4; ++q) {
            int row = (lane >> 4) * 4 + q;
            float v = fmaxf(fmaf(acc[tile][q], sc, sh), 0.0f);
            *(short*)(ldsb + row * 128 + ((col * 2) ^ ((row & 7) << 4))) = (short)f2bf(v);
        }
    }
    __syncthreads();

    // ---- GEMM2 + BN + ReLU ----
    {
        int rr = lane & 15;
        a0 = *(const short8*)(ldsb + rr * 128 + (((lane >> 4) * 16) ^ ((rr & 7) << 4)));
        a1 = *(const short8*)(ldsb + rr * 128 + ((64 + (lane >> 4) * 16) ^ ((rr & 7) << 4)));
    }
#pragma unroll
    for (int tile = 0; tile < 4; ++tile) {
        acc[tile] = (f32x4){0.f, 0.f, 0.f, 0.f};
        acc[tile] = __builtin_amdgcn_mfma_f32_16x16x32_bf16(a0, wfG2[(tile * 2 + 0) * 64 + lane], acc[tile], 0, 0, 0);
        acc[tile] = __builtin_amdgcn_mfma_f32_16x16x32_bf16(a1, wfG2[(tile * 2 + 1) * 64 + lane], acc[tile], 0, 0, 0);
    }
    __syncthreads();
#pragma unroll
    for (int tile = 0; tile < 4; ++tile) {
        int col = tile * 16 + (lane & 15);
        float sc = g2[col] * BN_RSQRT;
        float sh = fmaf(b2[col], sc, bt2[col]);
#pragma unroll
        for (int q = 0; q < 4; ++q) {
            int row = (lane >> 4) * 4 + q;
            float v = fmaxf(fmaf(acc[tile][q], sc, sh), 0.0f);
            *(short*)(ldsb + row * 128 + ((col * 2) ^ ((row & 7) << 4))) = (short)f2bf(v);
        }
    }
    __syncthreads();

    if (FINAL == 0) {
        // fp8-pack + store (row index from table; zero row excluded by guard)
#pragma unroll
        for (int half = 0; half < 2; ++half) {
            int row = (lane >> 3) + half * 8;
            short8 vv = *(const short8*)(ldsb + row * 128 + ((((lane & 7) * 16)) ^ ((row & 7) << 4)));
            int ro = idx_tab[wave][row][MAXD];
            if (ro < (nrows << 6)) {
                unsigned w0 = fp8_enc4(us2f((unsigned short)vv[0]), us2f((unsigned short)vv[1]),
                                       us2f((unsigned short)vv[2]), us2f((unsigned short)vv[3]));
                unsigned w1 = fp8_enc4(us2f((unsigned short)vv[4]), us2f((unsigned short)vv[5]),
                                       us2f((unsigned short)vv[6]), us2f((unsigned short)vv[7]));
                *(uint2*)(out + ro + (lane & 7) * 8) = make_uint2(w0, w1);
            }
        }
    } else {
        // ---- GEMM3: relu(h4 @ Wl1 + bl1) ----
        {
            int rr = lane & 15;
            a0 = *(const short8*)(ldsb + rr * 128 + (((lane >> 4) * 16) ^ ((rr & 7) << 4)));
            a1 = *(const short8*)(ldsb + rr * 128 + ((64 + (lane >> 4) * 16) ^ ((rr & 7) << 4)));
        }
#pragma unroll
        for (int tile = 0; tile < 4; ++tile) {
            acc[tile] = (f32x4){0.f, 0.f, 0.f, 0.f};
            acc[tile] = __builtin_amdgcn_mfma_f32_16x16x32_bf16(a0, wfL1[(tile * 2 + 0) * 64 + lane], acc[tile], 0, 0, 0);
            acc[tile] = __builtin_amdgcn_mfma_f32_16x16x32_bf16(a1, wfL1[(tile * 2 + 1) * 64 + lane], acc[tile], 0, 0, 0);
        }
        __syncthreads();
#pragma unroll
        for (int tile = 0; tile < 4; ++tile) {
            int col = tile * 16 + (lane & 15);
            float bia = bl1[col];
#pragma unroll
            for (int q = 0; q < 4; ++q) {
                int row = (lane >> 4) * 4 + q;
                float v = fmaxf(acc[tile][q] + bia, 0.0f);
                *(short*)(ldsb + row * 128 + ((col * 2) ^ ((row & 7) << 4))) = (short)f2bf(v);
            }
        }
        __syncthreads();
        // ---- in-kernel mean-pool partials (natural order, batch sorted) ----
        float pacc = 0.0f;
        int curg = -1, rc = 0;
        for (int r = 0; r < 16; ++r) {
            int row = r0 + r;
            if (row >= nrows) break;
            float v = us2f(*(const unsigned short*)(ldsb + r * 128 + ((lane * 2) ^ ((r & 7) << 4))));
            int g = batch[row];
            if (g != curg) {
                if (curg >= 0) {
                    atomicAdd(&pooled[curg * HH + lane], pacc);
                    if (lane == 0) atomicAdd(&cnt[curg], (float)rc);
                }
                curg = g; pacc = v; rc = 1;
            } else { pacc += v; rc += 1; }
        }
        if (curg >= 0) {
            atomicAdd(&pooled[curg * HH + lane], pacc);
            if (lane == 0) atomicAdd(&cnt[curg], (float)rc);
        }
    }
}

__global__ __launch_bounds__(64) void head_kernel(
    const float* __restrict__ pooled, const float* __restrict__ cnt,
    const float* __restrict__ Wl2, const float* __restrict__ bl2,
    float* __restrict__ out, int ngraphs)
{
    int gidx = blockIdx.x * 64 + threadIdx.x;
    if (gidx >= ngraphs) return;
    float logits[CC];
#pragma unroll
    for (int c = 0; c < CC; ++c) logits[c] = bl2[c];
    float inv_n = 1.0f / fmaxf(cnt[gidx], 1.0f);
    for (int k = 0; k < HH; ++k) {
        float p = pooled[gidx * HH + k] * inv_n;
#pragma unroll
        for (int c = 0; c < CC; ++c) logits[c] = fmaf(p, Wl2[k * CC + c], logits[c]);
    }
    float m = logits[0];
#pragma unroll
    for (int c = 1; c < CC; ++c) m = fmaxf(m, logits[c]);
    float ssum = 0.0f;
#pragma unroll
    for (int c = 0; c < CC; ++c) { logits[c] = __expf(logits[c] - m); ssum += logits[c]; }
    float inv = 1.0f / ssum;
#pragma unroll
    for (int c = 0; c < CC; ++c) out[gidx * CC + c] = logits[c] * inv;
}

extern "C" void kernel_launch(void* const* d_in, const int* in_sizes, int n_in,
                              void* d_out, int out_size, void* d_ws, size_t ws_size,
                              hipStream_t stream) {
    const float* x      = (const float*)d_in[0];
    const int*   ei     = (const int*)  d_in[1];
    const int*   batch  = (const int*)  d_in[3];
    const float* W0     = (const float*)d_in[4];
    const float* b0     = (const float*)d_in[5];
    const float* convW1 = (const float*)d_in[6];
    const float* convb1 = (const float*)d_in[7];
    const float* convg1 = (const float*)d_in[8];
    const float* convbt1= (const float*)d_in[9];
    const float* convW2 = (const float*)d_in[10];
    const float* convb2 = (const float*)d_in[11];
    const float* convg2 = (const float*)d_in[12];
    const float* convbt2= (const float*)d_in[13];
    const float* Wl1    = (const float*)d_in[14];
    const float* bl1    = (const float*)d_in[15];
    const float* Wl2    = (const float*)d_in[16];
    const float* bl2    = (const float*)d_in[17];

    const int N = in_sizes[0] / FF;
    const int E = in_sizes[1] / 2;
    const int G = out_size / CC;

    const int* src = ei;
    const int* dst = ei + E;

    size_t off = 0;
    auto take = [&](size_t bytes) { size_t p = off; off = (off + bytes + 255) & ~255ULL; return p; };
    int NB = (N + 255) / 256;
    int EB = (E + 255) / 256;
    size_t o_rowptr = take((size_t)N * 4);
    size_t o_deg    = take((size_t)N * 4);
    size_t o_csr    = take((size_t)(E > NB ? E : NB) * 4 + 512);
    size_t o_perm   = take((size_t)N * 4);
    size_t o_dhist  = take(64 * 4);
    size_t o_dcnt   = take(64 * 4);
    size_t o_pooled = take((size_t)G * HH * 4);
    size_t o_cnt    = take((size_t)G * 4);
    size_t o_wfrag  = take((size_t)5632 * 8 * 2);
    size_t o_hA     = take((size_t)(N + 1) * 64);
    size_t o_hB     = take((size_t)(N + 1) * 64);

    char* base = (char*)d_ws;
    int*    rowptr = (int*)(base + o_rowptr);
    int*    deg    = (int*)(base + o_deg);
    int*    csr    = (int*)(base + o_csr);
    int*    perm   = (int*)(base + o_perm);
    int*    dhist  = (int*)(base + o_dhist);
    int*    dcnt   = (int*)(base + o_dcnt);
    float*  pooled = (float*)(base + o_pooled);
    float*  cnt    = (float*)(base + o_cnt);
    short*  wfrag  = (short*)(base + o_wfrag);
    short8* wf8    = (short8*)wfrag;
    unsigned char* hA = (unsigned char*)(base + o_hA);
    unsigned char* hB = (unsigned char*)(base + o_hB);

    int tile_blocks = (N + 63) / 64;     // 4 waves x 16 rows

    // weight fragment packing
    pack_weights_kernel<<<22, 256, 0, stream>>>(W0, convW1, convW2, Wl1, wfrag);

    // CSR build
    (void)hipMemsetAsync(deg, 0, (size_t)N * sizeof(int), stream);
    hist_kernel<<<EB, 256, 0, stream>>>(dst, deg, E);
    scan_block_kernel<<<NB, 256, 0, stream>>>(deg, rowptr, csr /*partials*/, N);
    scan_partials_kernel<<<1, 256, 0, stream>>>(csr, NB);
    add_offsets_kernel<<<NB, 256, 0, stream>>>(rowptr, csr, N);
    (void)hipMemsetAsync(deg, 0, (size_t)N * sizeof(int), stream);
    {
        int stride = ((E + 3) / 4 + 255) & ~255;
        place_kernel<<<stride / 256, 256, 0, stream>>>(src, dst, rowptr, deg, csr, E, stride);
    }

    // degree bucketing (uses restored deg)
    (void)hipMemsetAsync(dhist, 0, 64 * sizeof(int), stream);
    deg_hist_kernel<<<NB, 256, 0, stream>>>(deg, dhist, N);
    bucket_scan_kernel<<<1, 64, 0, stream>>>(dhist, dcnt);
    perm_place_kernel<<<NB, 256, 0, stream>>>(deg, dcnt, perm, N);

    // zero rows (index N) of both h buffers
    (void)hipMemsetAsync(hA + (size_t)N * 64, 0, 64, stream);
    (void)hipMemsetAsync(hB + (size_t)N * 64, 0, 64, stream);

    // lin0
    lin0_kernel<<<tile_blocks, 256, 0, stream>>>(x, wf8, b0, hA, N);

    // pooled/cnt init
    (void)hipMemsetAsync(pooled, 0, (size_t)G * HH * sizeof(float), stream);
    (void)hipMemsetAsync(cnt, 0, (size_t)G * sizeof(float), stream);

    // layers (ping-pong); 0..2 degree-bucketed, last natural + fused pool
    const unsigned char* hin = hA; unsigned char* hout = hB;
    const short8* wfL1 = wf8 + 5120;
    for (int l = 0; l < LL; ++l) {
        const short8* wfG1 = wf8 + 1024 + (size_t)(l * 2 + 0) * 512;
        const short8* wfG2 = wf8 + 1024 + (size_t)(l * 2 + 1) * 512;
        if (l < LL - 1) {
            layer_kernel<0><<<tile_blocks, 256, 0, stream>>>(
                hin, rowptr, deg, csr, perm, wfG1, wfG2,
                convb1 + l * HH, convg1 + l * HH, convbt1 + l * HH,
                convb2 + l * HH, convg2 + l * HH, convbt2 + l * HH,
                hout, N, nullptr, nullptr, nullptr, nullptr, nullptr);
        } else {
            layer_kernel<1><<<tile_blocks, 256, 0, stream>>>(
                hin, rowptr, deg, csr, nullptr, wfG1, wfG2,
                convb1 + l * HH, convg1 + l * HH, convbt1 + l * HH,
                convb2 + l * HH, convg2 + l * HH, convbt2 + l * HH,
                nullptr, N, wfL1, bl1, batch, pooled, cnt);
        }
        unsigned char* tswap = (unsigned char*)hin; hin = hout; hout = tswap;
    }

    head_kernel<<<(G + 63) / 64, 64, 0, stream>>>(pooled, cnt, Wl2, bl2, (float*)d_out, G);
}